// Round 6
// baseline (454.213 us; speedup 1.0000x reference)
//
#include <hip/hip_runtime.h>
#include <math.h>

typedef __bf16 bf16;
typedef float f32x4 __attribute__((ext_vector_type(4)));
typedef float f32x16 __attribute__((ext_vector_type(16)));
typedef bf16 bf16x8 __attribute__((ext_vector_type(8)));
typedef bf16 bf16x4 __attribute__((ext_vector_type(4)));
typedef unsigned int u32;
typedef unsigned int u32x2 __attribute__((ext_vector_type(2)));

#define DEV __device__ __forceinline__

constexpr int Ss = 1024, Dd = 1024;
constexpr float EPSf = 1e-6f;
// softmax in log2 domain: scale = (1/sqrt(64)) * log2(e)
constexpr float SM_SCALE = 0.125f * 1.4426950408889634f;

// ---- async global->LDS, 16B per lane, wave-uniform LDS base ----
DEV void gl_lds16(const void* g, void* l) {
  __builtin_amdgcn_global_load_lds(
      (const __attribute__((address_space(1))) void*)g,
      (__attribute__((address_space(3))) void*)l, 16, 0, 0);
}

// pack 2 f32 -> 2 bf16 in one u32 (low = first arg)
DEV u32 cvtpk(float lo, float hi) {
  u32 r;
  asm("v_cvt_pk_bf16_f32 %0, %1, %2" : "=v"(r) : "v"(lo), "v"(hi));
  return r;
}

// =====================================================================
// All six weight transposes (fp32 (K,N) -> bf16 (N,K)) in ONE dispatch.
// =====================================================================
__global__ __launch_bounds__(256) void transpose6_k(
    const float* __restrict__ i0, const float* __restrict__ i1,
    const float* __restrict__ i2, const float* __restrict__ i3,
    const float* __restrict__ i4, const float* __restrict__ i5,
    bf16* __restrict__ o0, bf16* __restrict__ o1, bf16* __restrict__ o2,
    bf16* __restrict__ o3, bf16* __restrict__ o4, bf16* __restrict__ o5) {
  __shared__ float t[64 * 65];
  const int bi = blockIdx.x;
  const float* in;
  bf16* out;
  int R, C, local, sh;
  if (bi < 1024) {
    const int j = bi >> 8;
    local = bi & 255; R = 1024; C = 1024; sh = 4;
    in = (j == 0) ? i0 : (j == 1) ? i1 : (j == 2) ? i2 : i3;
    out = (j == 0) ? o0 : (j == 1) ? o1 : (j == 2) ? o2 : o3;
  } else if (bi < 2048) {
    local = bi - 1024; R = 1024; C = 4096; sh = 6; in = i4; out = o4;
  } else {
    local = bi - 2048; R = 4096; C = 1024; sh = 4; in = i5; out = o5;
  }
  const int nx = 1 << sh;
  const int bx = local & (nx - 1), by = local >> sh;
  const int tid = threadIdx.x;
  const int tx = tid & 63, ty = tid >> 6;
  const int r0 = by * 64, c0 = bx * 64;
#pragma unroll
  for (int i = 0; i < 16; i++) {
    int r = ty + i * 4;
    t[r * 65 + tx] = in[(size_t)(r0 + r) * C + c0 + tx];
  }
  __syncthreads();
#pragma unroll
  for (int i = 0; i < 16; i++) {
    int r = ty + i * 4;
    out[(size_t)(c0 + r) * R + r0 + tx] = (bf16)t[tx * 65 + r];
  }
}

// =====================================================================
// LayerNorm (ddof=1, scalar gamma/beta, /(std+eps)). fp32 in, bf16 out.
// =====================================================================
__global__ __launch_bounds__(256) void ln_kernel(
    const float* __restrict__ in, bf16* __restrict__ out,
    const float* __restrict__ gp, const float* __restrict__ bp) {
  const int row = blockIdx.x;
  const int tid = threadIdx.x;
  float v[4];
  const float* p = in + (size_t)row * Dd + tid * 4;
#pragma unroll
  for (int i = 0; i < 4; i++) v[i] = p[i];
  float s = v[0] + v[1] + v[2] + v[3];
  float s2 = v[0] * v[0] + v[1] * v[1] + v[2] * v[2] + v[3] * v[3];
#pragma unroll
  for (int m = 1; m < 64; m <<= 1) {
    s += __shfl_xor(s, m, 64);
    s2 += __shfl_xor(s2, m, 64);
  }
  __shared__ float ls[4], ls2[4];
  if ((tid & 63) == 0) {
    ls[tid >> 6] = s;
    ls2[tid >> 6] = s2;
  }
  __syncthreads();
  s = ls[0] + ls[1] + ls[2] + ls[3];
  s2 = ls2[0] + ls2[1] + ls2[2] + ls2[3];
  float mean = s * (1.0f / Dd);
  float var = (s2 - (float)Dd * mean * mean) * (1.0f / (Dd - 1));
  var = fmaxf(var, 0.0f);
  float g = gp[0], be = bp[0];
  float rs = g / (sqrtf(var) + EPSf);
  bf16* q = out + (size_t)row * Dd + tid * 4;
#pragma unroll
  for (int i = 0; i < 4; i++) q[i] = (bf16)((v[i] - mean) * rs + be);
}

// =====================================================================
// GEMM C = A(M,K; stride sa) @ Bt(N,K; stride sb)^T + epilogue.
// 128x128 tile, templated BK, 4 waves, 4x4 MFMA 16x16x32, XOR swizzle.
// XCD-aware block remap (T1).
// EPI: 1 bias+resid(f32)->f32 | 2 bias,relu->bf16 | 3 resid(f32)->f32
//      4 qkv 3-way bias; Q,K -> bf16 Cout, V -> LDS-transposed
//        coalesced store into vtb (requires BK==64: T uses 32KB smem)
// =====================================================================
template <int EPI, int BK>
__global__ __launch_bounds__(256) void gemm_bt(
    const bf16* __restrict__ A, const bf16* __restrict__ Bt,
    const float* __restrict__ bias, const float* __restrict__ bias2,
    const float* __restrict__ bias3, const float* __restrict__ resid,
    bf16* __restrict__ vtb, void* __restrict__ Cout, int M, int N, int K,
    int sa, int sb) {
  __shared__ __attribute__((aligned(16))) char smem[2 * 128 * BK * 2];
  bf16* As = (bf16*)smem;
  bf16* Bs = (bf16*)(smem + 128 * BK * 2);
  constexpr int CPR = BK / 8;       // 8-elem chunks per row
  constexpr int RPJ = 256 / CPR;    // rows staged per j-iteration
  constexpr int NJ = BK / 16;       // j-iterations per operand
  const int tid = threadIdx.x;
  const int ln = tid & 63;
  const int wv = tid >> 6;
  const int wm = wv >> 1, wn = wv & 1;
  const int quad = ln >> 4, l16 = ln & 15;
  const int l7 = l16 & 7;
  // T1 XCD-aware remap (dispatch order is x-fastest; XCD ~ d % 8)
  const int nxg = gridDim.x;
  const int d = blockIdx.y * nxg + blockIdx.x;
  const int sseq = d >> 3;
  const int bxr = sseq % nxg;
  const int byr = (d & 7) + 8 * (sseq / nxg);
  const int m0 = byr * 128, n0 = bxr * 128;

  f32x4 acc[4][4];
#pragma unroll
  for (int i = 0; i < 4; i++)
#pragma unroll
    for (int j = 0; j < 4; j++) acc[i][j] = {0.f, 0.f, 0.f, 0.f};

  const int sr = tid / CPR;                    // staging row (within j-blk)
  const int sc = (tid & (CPR - 1)) ^ (sr & 7); // swizzled source chunk
  const size_t abase = (size_t)(m0 + sr) * sa + sc * 8;
  const size_t bbase = (size_t)(n0 + sr) * sb + sc * 8;

  for (int k0 = 0; k0 < K; k0 += BK) {
#pragma unroll
    for (int j = 0; j < NJ; j++) {
      gl_lds16(A + abase + (size_t)(j * RPJ) * sa + k0,
               (char*)As + j * 4096 + wv * 1024);
      gl_lds16(Bt + bbase + (size_t)(j * RPJ) * sb + k0,
               (char*)Bs + j * 4096 + wv * 1024);
    }
    __syncthreads();
#pragma unroll
    for (int kh = 0; kh < BK / 32; kh++) {
      bf16x8 af[4], bfr[4];
#pragma unroll
      for (int mi = 0; mi < 4; mi++)
        af[mi] = *(const bf16x8*)&As[(wm * 64 + mi * 16 + l16) * BK +
                                     ((kh * 4 + quad) ^ l7) * 8];
#pragma unroll
      for (int ni = 0; ni < 4; ni++)
        bfr[ni] = *(const bf16x8*)&Bs[(wn * 64 + ni * 16 + l16) * BK +
                                      ((kh * 4 + quad) ^ l7) * 8];
#pragma unroll
      for (int mi = 0; mi < 4; mi++)
#pragma unroll
        for (int ni = 0; ni < 4; ni++)
          acc[mi][ni] = __builtin_amdgcn_mfma_f32_16x16x32_bf16(
              af[mi], bfr[ni], acc[mi][ni], 0, 0, 0);
    }
    __syncthreads();
  }

  if constexpr (EPI == 4) {
    if (n0 < 2048) {  // Q,K -> qkv buffer (direct bf16 stores)
#pragma unroll
      for (int mi = 0; mi < 4; mi++) {
        const int m = m0 + wm * 64 + mi * 16 + quad * 4;
#pragma unroll
        for (int ni = 0; ni < 4; ni++) {
          const int n = n0 + wn * 64 + ni * 16 + l16;
          const float bvl = (n < 1024) ? bias[n] : bias2[n - 1024];
#pragma unroll
          for (int r = 0; r < 4; r++)
            ((bf16*)Cout)[(size_t)(m + r) * N + n] =
                (bf16)(acc[mi][ni][r] + bvl);
        }
      }
    } else {  // V: transpose 128x128 tile via LDS, coalesced store to vtb
      bf16* T = (bf16*)smem;  // [128][128] bf16 = 32 KB (BK must be 64)
#pragma unroll
      for (int mi = 0; mi < 4; mi++) {
        const int ml = wm * 64 + mi * 16 + quad * 4;  // local row, 4-contig
        const int c = ml >> 3, hf = (ml >> 2) & 1;
#pragma unroll
        for (int ni = 0; ni < 4; ni++) {
          const int nl = wn * 64 + ni * 16 + l16;  // local col
          const float bvl = bias3[(n0 - 2048) + nl];
          bf16x4 tv;
#pragma unroll
          for (int r = 0; r < 4; r++) tv[r] = (bf16)(acc[mi][ni][r] + bvl);
          *(bf16x4*)&T[nl * 128 + ((c ^ (nl & 15)) << 3) + (hf << 2)] = tv;
        }
      }
      __syncthreads();
      const size_t vbase =
          ((size_t)(m0 >> 10) * 1024 + (n0 - 2048)) * Ss + (m0 & 1023);
#pragma unroll
      for (int p = 0; p < 8; p++) {
        const int row = p * 16 + (tid >> 4);
        const int k = tid & 15;
        bf16x8 vv = *(const bf16x8*)&T[row * 128 + ((k ^ (row & 15)) << 3)];
        *(bf16x8*)&vtb[vbase + (size_t)row * Ss + k * 8] = vv;
      }
    }
  } else {
#pragma unroll
    for (int mi = 0; mi < 4; mi++) {
      const int m = m0 + wm * 64 + mi * 16 + quad * 4;
#pragma unroll
      for (int ni = 0; ni < 4; ni++) {
        const int n = n0 + wn * 64 + ni * 16 + l16;
        float bvl = 0.0f;
        if constexpr (EPI != 3) bvl = bias[n];
#pragma unroll
        for (int r = 0; r < 4; r++) {
          float val = acc[mi][ni][r] + bvl;
          const size_t idx = (size_t)(m + r) * N + n;
          if constexpr (EPI == 1) {
            ((float*)Cout)[idx] = val + resid[idx];
          } else if constexpr (EPI == 2) {
            ((bf16*)Cout)[idx] = (bf16)fmaxf(val, 0.0f);
          } else {
            ((float*)Cout)[idx] = val + resid[idx];
          }
        }
      }
    }
  }
}

// =====================================================================
// gemm256_relu v3: 4-phase interleave, RACE-FIXED staging order.
// Read-need analysis: next-tile ph0 reads ALL B chunks (each wn-band's
// first half) + A chunks 0,2; ph1 reads A chunks 1,3 only. So only A
// chunks 1,3 may remain in flight across the tile boundary.
// Stage order: ph0 -> B chunks 0,1 | ph1 -> B chunks 2,3
//              ph2 -> A chunks 0,2 | ph3 -> A chunks 1,3
// Waits (per-wave, before the closing barrier -> mutual guarantee):
//   end-ph0 vmcnt(2): drains prev tile's A1,A3 (outstanding
//     {a1',a3',b0,b1}) before ph1 reads those chunks.
//   end-ph3 vmcnt(2): drains b0-3,a0,a2; leaves a1,a3 flying.
// Last tile: vmcnt(0) at both points (uniform scalar branch).
// =====================================================================
__global__ __launch_bounds__(512) void gemm256_relu(
    const bf16* __restrict__ A, const bf16* __restrict__ Bt,
    const float* __restrict__ bias, bf16* __restrict__ Cout, int M, int N,
    int K, int sa, int sb) {
  __shared__ __attribute__((aligned(16))) char smem[131072];
  const int tid = threadIdx.x;
  const int ln = tid & 63;
  const int wv = tid >> 6;  // 0..7
  const int wm = wv >> 2, wn = wv & 3;
  const int quad = ln >> 4, l16 = ln & 15;
  const int l7 = l16 & 7;
  // T1 XCD-aware remap
  const int nxg = gridDim.x;
  const int d = blockIdx.y * nxg + blockIdx.x;
  const int sseq = d >> 3;
  const int bxr = sseq % nxg;
  const int byr = (d & 7) + 8 * (sseq / nxg);
  const int m0 = byr * 256, n0 = bxr * 256;

  f32x4 acc[8][4];
#pragma unroll
  for (int i = 0; i < 8; i++)
#pragma unroll
    for (int j = 0; j < 4; j++) acc[i][j] = {0.f, 0.f, 0.f, 0.f};

  const int sr = tid >> 3;              // staging row 0..63 (per chunk)
  const int sc = (tid & 7) ^ (sr & 7);  // swizzled source chunk
  const size_t abase = (size_t)(m0 + sr) * sa + sc * 8;
  const size_t bbase = (size_t)(n0 + sr) * sb + sc * 8;
  const int w8 = tid >> 6;  // wave-uniform LDS sub-base

  const int nt = K >> 6;
  int cur = 0;

  // prologue: stage tile 0 into buffer 0, full drain once
  {
#pragma unroll
    for (int j = 0; j < 4; j++) {
      gl_lds16(A + abase + (size_t)(j * 64) * sa,
               smem + j * 8192 + w8 * 1024);
      gl_lds16(Bt + bbase + (size_t)(j * 64) * sb,
               smem + 32768 + j * 8192 + w8 * 1024);
    }
  }
  asm volatile("s_waitcnt vmcnt(0)" ::: "memory");
  __builtin_amdgcn_s_barrier();

  for (int t = 0; t < nt; ++t) {
    const bf16* As = (const bf16*)(smem + cur * 65536);
    const bf16* Bs = (const bf16*)(smem + cur * 65536 + 32768);
    char* ldst = smem + (cur ^ 1) * 65536;
    const bool pf = (t + 1 < nt);
    const int koff = (t + 1) * 64;

    bf16x8 af[4][2], bfr[2][2];

    // -------- phase 0: read A(mh0)+B(nq0); stage B chunks 0,1 --------
#pragma unroll
    for (int mf = 0; mf < 4; mf++)
#pragma unroll
      for (int kh = 0; kh < 2; kh++)
        af[mf][kh] = *(const bf16x8*)&As[(wm * 128 + mf * 16 + l16) * 64 +
                                         (((kh * 4 + quad) ^ l7) * 8)];
#pragma unroll
    for (int nf = 0; nf < 2; nf++)
#pragma unroll
      for (int kh = 0; kh < 2; kh++)
        bfr[nf][kh] = *(const bf16x8*)&Bs[(wn * 64 + nf * 16 + l16) * 64 +
                                          (((kh * 4 + quad) ^ l7) * 8)];
    if (pf) {
      gl_lds16(Bt + bbase + koff, ldst + 32768 + w8 * 1024);
      gl_lds16(Bt + bbase + (size_t)64 * sb + koff,
               ldst + 32768 + 8192 + w8 * 1024);
    }
    __builtin_amdgcn_s_barrier();
    __builtin_amdgcn_s_setprio(1);
#pragma unroll
    for (int mf = 0; mf < 4; mf++)
#pragma unroll
      for (int nf = 0; nf < 2; nf++)
#pragma unroll
        for (int kh = 0; kh < 2; kh++)
          acc[mf][nf] = __builtin_amdgcn_mfma_f32_16x16x32_bf16(
              af[mf][kh], bfr[nf][kh], acc[mf][nf], 0, 0, 0);
    __builtin_amdgcn_s_setprio(0);
    // prev tile's A chunks 1,3 must land before ph1 reads them
    if (pf) {
      asm volatile("s_waitcnt vmcnt(2)" ::: "memory");
    } else {
      asm volatile("s_waitcnt vmcnt(0)" ::: "memory");
    }
    __builtin_amdgcn_s_barrier();

    // -------- phase 1: read A(mh1); stage B chunks 2,3 --------
#pragma unroll
    for (int mf = 0; mf < 4; mf++)
#pragma unroll
      for (int kh = 0; kh < 2; kh++)
        af[mf][kh] =
            *(const bf16x8*)&As[(wm * 128 + 64 + mf * 16 + l16) * 64 +
                                (((kh * 4 + quad) ^ l7) * 8)];
    if (pf) {
      gl_lds16(Bt + bbase + (size_t)128 * sb + koff,
               ldst + 32768 + 16384 + w8 * 1024);
      gl_lds16(Bt + bbase + (size_t)192 * sb + koff,
               ldst + 32768 + 24576 + w8 * 1024);
    }
    __builtin_amdgcn_s_barrier();
    __builtin_amdgcn_s_setprio(1);
#pragma unroll
    for (int mf = 0; mf < 4; mf++)
#pragma unroll
      for (int nf = 0; nf < 2; nf++)
#pragma unroll
        for (int kh = 0; kh < 2; kh++)
          acc[4 + mf][nf] = __builtin_amdgcn_mfma_f32_16x16x32_bf16(
              af[mf][kh], bfr[nf][kh], acc[4 + mf][nf], 0, 0, 0);
    __builtin_amdgcn_s_setprio(0);
    __builtin_amdgcn_s_barrier();

    // -------- phase 2: read B(nq1); stage A chunks 0,2 --------
#pragma unroll
    for (int nf = 0; nf < 2; nf++)
#pragma unroll
      for (int kh = 0; kh < 2; kh++)
        bfr[nf][kh] =
            *(const bf16x8*)&Bs[(wn * 64 + 32 + nf * 16 + l16) * 64 +
                                (((kh * 4 + quad) ^ l7) * 8)];
    if (pf) {
      gl_lds16(A + abase + koff, ldst + w8 * 1024);
      gl_lds16(A + abase + (size_t)128 * sa + koff,
               ldst + 16384 + w8 * 1024);
    }
    __builtin_amdgcn_s_barrier();
    __builtin_amdgcn_s_setprio(1);
#pragma unroll
    for (int mf = 0; mf < 4; mf++)
#pragma unroll
      for (int nf = 0; nf < 2; nf++)
#pragma unroll
        for (int kh = 0; kh < 2; kh++)
          acc[4 + mf][2 + nf] = __builtin_amdgcn_mfma_f32_16x16x32_bf16(
              af[mf][kh], bfr[nf][kh], acc[4 + mf][2 + nf], 0, 0, 0);
    __builtin_amdgcn_s_setprio(0);
    __builtin_amdgcn_s_barrier();

    // -------- phase 3: read A(mh0) again; stage A chunks 1,3 --------
#pragma unroll
    for (int mf = 0; mf < 4; mf++)
#pragma unroll
      for (int kh = 0; kh < 2; kh++)
        af[mf][kh] = *(const bf16x8*)&As[(wm * 128 + mf * 16 + l16) * 64 +
                                         (((kh * 4 + quad) ^ l7) * 8)];
    if (pf) {
      gl_lds16(A + abase + (size_t)64 * sa + koff, ldst + 8192 + w8 * 1024);
      gl_lds16(A + abase + (size_t)192 * sa + koff,
               ldst + 24576 + w8 * 1024);
    }
    __builtin_amdgcn_s_barrier();
    __builtin_amdgcn_s_setprio(1);
#pragma unroll
    for (int mf = 0; mf < 4; mf++)
#pragma unroll
      for (int nf = 0; nf < 2; nf++)
#pragma unroll
        for (int kh = 0; kh < 2; kh++)
          acc[mf][2 + nf] = __builtin_amdgcn_mfma_f32_16x16x32_bf16(
              af[mf][kh], bfr[nf][kh], acc[mf][2 + nf], 0, 0, 0);
    __builtin_amdgcn_s_setprio(0);
    // boundary: everything except the fresh A1,A3 pair must be landed
    if (pf) {
      asm volatile("s_waitcnt vmcnt(2)" ::: "memory");
    } else {
      asm volatile("s_waitcnt vmcnt(0)" ::: "memory");
    }
    __builtin_amdgcn_s_barrier();
    cur ^= 1;
  }

  // epilogue: bias + relu -> bf16
#pragma unroll
  for (int mi = 0; mi < 8; mi++) {
    const int m = m0 + wm * 128 + mi * 16 + quad * 4;
#pragma unroll
    for (int ni = 0; ni < 4; ni++) {
      const int n = n0 + wn * 64 + ni * 16 + l16;
      const float bvl = bias[n];
#pragma unroll
      for (int r = 0; r < 4; r++)
        Cout[(size_t)(m + r) * N + n] =
            (bf16)fmaxf(acc[mi][ni][r] + bvl, 0.0f);
    }
  }
}

// =====================================================================
// Flash attention v2: swapped QK^T (S^T = K·Q^T) on 32x32x16 MFMA.
// =====================================================================
__global__ __launch_bounds__(256) void attn_k(
    const bf16* __restrict__ qkv, const bf16* __restrict__ vt,
    const int* __restrict__ mask, bf16* __restrict__ ctx) {
  __shared__ __attribute__((aligned(16))) char smem[36864];
  __shared__ int Ft[16];
  bf16* Qs = (bf16*)smem;              // 16 KB (epilogue: transpose buf)
  bf16* Ks = (bf16*)(smem + 16384);    // 8 KB
  bf16* Vs = (bf16*)(smem + 24576);    // 8 KB
  float* Fm = (float*)(smem + 32768);  // 4 KB
  const int tid = threadIdx.x;
  const int l = tid & 63, w = tid >> 6;
  const int lq = l & 31, lh = l >> 5;
  const int lq7 = lq & 7;
  const int bh = blockIdx.x;
  const int b = bh >> 4, h = bh & 15;
  const int q0 = blockIdx.y * 128;
  const int sr = tid >> 3;              // staging row 0..31
  const int sc = (tid & 7) ^ (sr & 7);  // swizzled source chunk

  if (tid < 16) Ft[tid] = 0;
  {  // stage Q tile: 128 rows x 64 cols (async)
#pragma unroll
    for (int j = 0; j < 4; j++) {
      const size_t ga =
          (size_t)(b * Ss + q0 + j * 32 + sr) * 3072 + h * 64 + sc * 8;
      gl_lds16(qkv + ga, (char*)Qs + j * 4096 + w * 1024);
    }
  }
  __syncthreads();  // Ft init visible; Q staged (vmcnt drained)

  // Q B-fragments: col q = w*32+lq, k-elems d = s*16 + 8*lh + 0..7
  bf16x8 qf[4];
#pragma unroll
  for (int s = 0; s < 4; s++)
    qf[s] =
        *(const bf16x8*)&Qs[(w * 32 + lq) * 64 + (((s * 2 + lh) ^ lq7) * 8)];

  {  // mask -> additive log2-domain bias (0 or -inf) + per-tile flags
    const int4 mv = *(const int4*)&mask[b * Ss + tid * 4];
    const float ninf = -__builtin_inff();
    Fm[tid * 4 + 0] = mv.x ? 0.0f : ninf;
    Fm[tid * 4 + 1] = mv.y ? 0.0f : ninf;
    Fm[tid * 4 + 2] = mv.z ? 0.0f : ninf;
    Fm[tid * 4 + 3] = mv.w ? 0.0f : ninf;
    if (!(mv.x && mv.y && mv.z && mv.w)) atomicOr(&Ft[tid >> 4], 1);
  }

  f32x16 oacc[2];
#pragma unroll
  for (int d = 0; d < 2; d++)
#pragma unroll
    for (int r = 0; r < 16; r++) oacc[d][r] = 0.0f;
  float rsum = 0.0f;

  for (int kk0 = 0; kk0 < Ss; kk0 += 64) {
    {  // stage K (64 keys x 64 d) and Vt (64 d x 64 keys)
#pragma unroll
      for (int j = 0; j < 2; j++) {
        const size_t ga = (size_t)(b * Ss + kk0 + j * 32 + sr) * 3072 + 1024 +
                          h * 64 + sc * 8;
        gl_lds16(qkv + ga, (char*)Ks + j * 4096 + w * 1024);
        const size_t gv = (size_t)(bh * 64 + j * 32 + sr) * Ss + kk0 + sc * 8;
        gl_lds16(vt + gv, (char*)Vs + j * 4096 + w * 1024);
      }
    }
    __syncthreads();  // K/V ready; Fm/Ft visible (first iter)

    // S^T[key][q]: A = K rows (keys), B = Q cols (q). C: col=lane&31=q,
    // row(key) = (reg&3) + 8*(reg>>2) + 4*(lane>>5).
    f32x16 sacc[2];
#pragma unroll
    for (int kb = 0; kb < 2; kb++)
#pragma unroll
      for (int r = 0; r < 16; r++) sacc[kb][r] = 0.0f;

    __builtin_amdgcn_s_setprio(1);
#pragma unroll
    for (int kb = 0; kb < 2; kb++)
#pragma unroll
      for (int s = 0; s < 4; s++) {
        const bf16x8 kf = *(const bf16x8*)&Ks[(kb * 32 + lq) * 64 +
                                              (((s * 2 + lh) ^ lq7) * 8)];
        sacc[kb] = __builtin_amdgcn_mfma_f32_32x32x16_bf16(kf, qf[s],
                                                           sacc[kb], 0, 0, 0);
      }
    __builtin_amdgcn_s_setprio(0);

    if (__builtin_amdgcn_readfirstlane(Ft[kk0 >> 6])) {
      // slow path: additive mask per key
#pragma unroll
      for (int kb = 0; kb < 2; kb++)
#pragma unroll
        for (int g = 0; g < 4; g++) {
          const f32x4 mv = *(const f32x4*)&Fm[kk0 + kb * 32 + 4 * lh + 8 * g];
#pragma unroll
          for (int j = 0; j < 4; j++)
            sacc[kb][g * 4 + j] = __builtin_amdgcn_exp2f(
                fmaf(sacc[kb][g * 4 + j], SM_SCALE, mv[j]));
        }
    } else {
#pragma unroll
      for (int kb = 0; kb < 2; kb++)
#pragma unroll
        for (int r = 0; r < 16; r++)
          sacc[kb][r] = __builtin_amdgcn_exp2f(sacc[kb][r] * SM_SCALE);
    }
    // rowsum (balanced tree; cross-half combined after the loop)
#pragma unroll
    for (int kb = 0; kb < 2; kb++) {
      const float t0 = (sacc[kb][0] + sacc[kb][1]) + (sacc[kb][2] + sacc[kb][3]);
      const float t1 = (sacc[kb][4] + sacc[kb][5]) + (sacc[kb][6] + sacc[kb][7]);
      const float t2 =
          (sacc[kb][8] + sacc[kb][9]) + (sacc[kb][10] + sacc[kb][11]);
      const float t3 =
          (sacc[kb][12] + sacc[kb][13]) + (sacc[kb][14] + sacc[kb][15]);
      rsum += ((t0 + t1) + (t2 + t3));
    }

    // pack P^T to bf16 B-frags in-register and run PV on the fly
    __builtin_amdgcn_s_setprio(1);
#pragma unroll
    for (int t = 0; t < 4; t++) {
      const int kb = t >> 1, rb = (t & 1) * 8;
      u32 pa = cvtpk(sacc[kb][rb + 0], sacc[kb][rb + 1]);  // keys {0,1}+4lh
      u32 pbv = cvtpk(sacc[kb][rb + 2], sacc[kb][rb + 3]); // keys {2,3}+4lh
      u32 pc = cvtpk(sacc[kb][rb + 4], sacc[kb][rb + 5]);  // keys {8,9}+4lh
      u32 pd = cvtpk(sacc[kb][rb + 6], sacc[kb][rb + 7]);  // keys {10,11}+4lh
      // swap upper half of first with lower half of second:
      // pa -> [a_lo|c_lo] (word0), pc -> [a_hi|c_hi] (word2)
      asm("v_permlane32_swap_b32 %0, %1" : "+v"(pa), "+v"(pc));
      asm("v_permlane32_swap_b32 %0, %1" : "+v"(pbv), "+v"(pd));
      union {
        u32 u[4];
        bf16x8 v;
      } pk;
      pk.u[0] = pa;
      pk.u[1] = pbv;
      pk.u[2] = pc;
      pk.u[3] = pd;
      const int vsw = ((t * 2 + lh) ^ lq7) * 8;
      const bf16x8 vf0 = *(const bf16x8*)&Vs[lq * 64 + vsw];
      const bf16x8 vf1 = *(const bf16x8*)&Vs[(32 + lq) * 64 + vsw];
      oacc[0] =
          __builtin_amdgcn_mfma_f32_32x32x16_bf16(vf0, pk.v, oacc[0], 0, 0, 0);
      oacc[1] =
          __builtin_amdgcn_mfma_f32_32x32x16_bf16(vf1, pk.v, oacc[1], 0, 0, 0);
    }
    __builtin_amdgcn_s_setprio(0);
    __syncthreads();
  }

  // combine the two lane-halves' partial rowsums (semantics-invariant)
  float xs = rsum, ys = rsum;
  asm("v_permlane32_swap_b32 %0, %1" : "+v"(xs), "+v"(ys));
  const float inv = 1.0f / (xs + ys);

  // epilogue: per-wave LDS transpose (stride 72 kills bank conflicts),
  // then coalesced 16B global stores. All smem dead after final barrier.
  bf16* Tb = (bf16*)(smem + w * 4608);  // 32 rows x 72 bf16 = 4608 B
#pragma unroll
  for (int dblk = 0; dblk < 2; dblk++)
#pragma unroll
    for (int g = 0; g < 4; g++) {
      const u32 lo =
          cvtpk(oacc[dblk][g * 4 + 0] * inv, oacc[dblk][g * 4 + 1] * inv);
      const u32 hi =
          cvtpk(oacc[dblk][g * 4 + 2] * inv, oacc[dblk][g * 4 + 3] * inv);
      u32x2 pr2;
      pr2[0] = lo;
      pr2[1] = hi;
      const int dbase = dblk * 32 + 8 * g + 4 * lh;
      *(u32x2*)&Tb[lq * 72 + dbase] = pr2;
    }
  __syncthreads();
#pragma unroll
  for (int p = 0; p < 4; p++) {
    const int row = p * 8 + (l >> 3);
    const int ch = l & 7;
    const bf16x8 vv = *(const bf16x8*)&Tb[row * 72 + ch * 8];
    *(bf16x8*)&ctx[(size_t)(b * Ss + q0 + w * 32 + row) * Dd + h * 64 +
                   ch * 8] = vv;
  }
}

// =====================================================================
extern "C" void kernel_launch(void* const* d_in, const int* in_sizes, int n_in,
                              void* d_out, int out_size, void* d_ws,
                              size_t ws_size, hipStream_t stream) {
  (void)in_sizes; (void)n_in; (void)out_size;
  const float* x = (const float*)d_in[0];
  const int* mask = (const int*)d_in[1];
  const float* wq = (const float*)d_in[2];
  const float* bq = (const float*)d_in[3];
  const float* wk = (const float*)d_in[4];
  const float* bk = (const float*)d_in[5];
  const float* wvw = (const float*)d_in[6];
  const float* bv = (const float*)d_in[7];
  const float* wo = (const float*)d_in[8];
  const float* bo = (const float*)d_in[9];
  const float* w1 = (const float*)d_in[10];
  const float* b1 = (const float*)d_in[11];
  const float* w2 = (const float*)d_in[12];
  const float* b2 = (const float*)d_in[13];
  const float* g1 = (const float*)d_in[14];
  const float* be1 = (const float*)d_in[15];
  const float* g2 = (const float*)d_in[16];
  const float* be2 = (const float*)d_in[17];
  float* out = (float*)d_out;

  char* ws = (char*)d_ws;
  const size_t MB = 1024 * 1024;
  bf16* w1T = (bf16*)(ws + 0 * MB);     // 8 MB  (4096x1024)
  bf16* w2T = (bf16*)(ws + 8 * MB);     // 8 MB  (1024x4096)
  bf16* wqkvT = (bf16*)(ws + 16 * MB);  // 6 MB  (3072x1024)
  bf16* woT = (bf16*)(ws + 22 * MB);    // 2 MB
  bf16* lnb = (bf16*)(ws + 24 * MB);    // 16 MB (ln1 -> ctx -> ln2)
  bf16* qkv = (bf16*)(ws + 40 * MB);    // 48 MB (8192x3072; V slots unused)
  bf16* vtb = (bf16*)(ws + 88 * MB);    // 16 MB
  float* x1 = (float*)(ws + 40 * MB);   // 32 MB overlay (qkv dead post-WO-in)
  bf16* ctx = lnb;                      // lnb dead after QKV GEMM

  dim3 blk(256);
  transpose6_k<<<3072, blk, 0, stream>>>(
      wq, wk, wvw, wo, w1, w2, wqkvT, wqkvT + (size_t)1024 * 1024,
      wqkvT + (size_t)2048 * 1024, woT, w1T, w2T);
  // LN1 (fp32 x -> bf16)
  ln_kernel<<<8192, blk, 0, stream>>>(x, lnb, g1, be1);
  // fused QKV projection; V transposed via LDS into vtb (coalesced)
  gemm_bt<4, 64><<<dim3(24, 64), blk, 0, stream>>>(
      lnb, wqkvT, bq, bk, bv, nullptr, vtb, qkv, 8192, 3072, 1024, 1024, 1024);
  // attention: grid (bh, qtile) -> q-tiles of one head share an XCD L2
  attn_k<<<dim3(128, 8), blk, 0, stream>>>(qkv, vtb, mask, ctx);
  // WO + bias + residual(x fp32) -> x1 (grid-capped 2 blk/CU -> BK=128)
  gemm_bt<1, 128><<<dim3(8, 64), blk, 0, stream>>>(
      ctx, woT, bo, nullptr, nullptr, x, nullptr, x1, 8192, 1024, 1024, 1024,
      1024);
  // LN2
  ln_kernel<<<8192, blk, 0, stream>>>(x1, lnb, g2, be2);

  if (ws_size >= 136 * MB) {
    // single-shot FFN: mid = 8192x4096 bf16 at 72..136 MB
    bf16* mid = (bf16*)(ws + 72 * MB);
    // FFN1 on the 256x256 4-phase counted-vmcnt pipeline
    gemm256_relu<<<dim3(16, 32), dim3(512), 0, stream>>>(
        lnb, w1T, b1, mid, 8192, 4096, 1024, 1024, 1024);
    gemm_bt<1, 128><<<dim3(8, 64), blk, 0, stream>>>(
        mid, w2T, b2, nullptr, nullptr, x1, nullptr, out, 8192, 1024, 4096,
        4096, 4096);
  } else {
    // chunked FFN (DFF=2048 halves), mid = 32 MB at 72..104 MB
    bf16* mid = (bf16*)(ws + 72 * MB);
    gemm256_relu<<<dim3(8, 32), dim3(512), 0, stream>>>(
        lnb, w1T, b1, mid, 8192, 2048, 1024, 1024, 1024);
    gemm_bt<1, 128><<<dim3(8, 64), blk, 0, stream>>>(
        mid, w2T, b2, nullptr, nullptr, x1, nullptr, out, 8192, 1024, 2048,
        2048, 4096);
    gemm256_relu<<<dim3(8, 32), dim3(512), 0, stream>>>(
        lnb, w1T + (size_t)2048 * 1024, b1 + 2048, mid, 8192, 2048, 1024,
        1024, 1024);
    gemm_bt<3, 128><<<dim3(8, 64), blk, 0, stream>>>(
        mid, w2T + 2048, nullptr, nullptr, nullptr, out, nullptr, out, 8192,
        1024, 2048, 2048, 4096);
  }
}

// Round 7
// 453.607 us; speedup vs baseline: 1.0013x; 1.0013x over previous
//
#include <hip/hip_runtime.h>
#include <math.h>

typedef __bf16 bf16;
typedef float f32x4 __attribute__((ext_vector_type(4)));
typedef float f32x16 __attribute__((ext_vector_type(16)));
typedef bf16 bf16x8 __attribute__((ext_vector_type(8)));
typedef bf16 bf16x4 __attribute__((ext_vector_type(4)));
typedef unsigned int u32;
typedef unsigned int u32x2 __attribute__((ext_vector_type(2)));

#define DEV __device__ __forceinline__

constexpr int Ss = 1024, Dd = 1024;
constexpr float EPSf = 1e-6f;
// softmax in log2 domain: scale = (1/sqrt(64)) * log2(e)
constexpr float SM_SCALE = 0.125f * 1.4426950408889634f;

// ---- async global->LDS, 16B per lane, wave-uniform LDS base ----
DEV void gl_lds16(const void* g, void* l) {
  __builtin_amdgcn_global_load_lds(
      (const __attribute__((address_space(1))) void*)g,
      (__attribute__((address_space(3))) void*)l, 16, 0, 0);
}

// pack 2 f32 -> 2 bf16 in one u32 (low = first arg)
DEV u32 cvtpk(float lo, float hi) {
  u32 r;
  asm("v_cvt_pk_bf16_f32 %0, %1, %2" : "=v"(r) : "v"(lo), "v"(hi));
  return r;
}

// =====================================================================
// Fused: six weight transposes (fp32 (K,N) -> bf16 (N,K)) + LN1.
// Blocks [0,3072) do transpose tiles; [3072, 3072+8192) do LN rows.
// =====================================================================
__global__ __launch_bounds__(256) void prep_k(
    const float* __restrict__ i0, const float* __restrict__ i1,
    const float* __restrict__ i2, const float* __restrict__ i3,
    const float* __restrict__ i4, const float* __restrict__ i5,
    bf16* __restrict__ o0, bf16* __restrict__ o1, bf16* __restrict__ o2,
    bf16* __restrict__ o3, bf16* __restrict__ o4, bf16* __restrict__ o5,
    const float* __restrict__ xin, bf16* __restrict__ lnout,
    const float* __restrict__ gp, const float* __restrict__ bp) {
  const int bi = blockIdx.x;
  const int tid = threadIdx.x;
  if (bi >= 3072) {
    // ---------------- LayerNorm (ddof=1, scalar gamma/beta) ----------
    const int row = bi - 3072;
    float v[4];
    const float* p = xin + (size_t)row * Dd + tid * 4;
#pragma unroll
    for (int i = 0; i < 4; i++) v[i] = p[i];
    float s = v[0] + v[1] + v[2] + v[3];
    float s2 = v[0] * v[0] + v[1] * v[1] + v[2] * v[2] + v[3] * v[3];
#pragma unroll
    for (int m = 1; m < 64; m <<= 1) {
      s += __shfl_xor(s, m, 64);
      s2 += __shfl_xor(s2, m, 64);
    }
    __shared__ float ls[4], ls2[4];
    if ((tid & 63) == 0) {
      ls[tid >> 6] = s;
      ls2[tid >> 6] = s2;
    }
    __syncthreads();
    s = ls[0] + ls[1] + ls[2] + ls[3];
    s2 = ls2[0] + ls2[1] + ls2[2] + ls2[3];
    float mean = s * (1.0f / Dd);
    float var = (s2 - (float)Dd * mean * mean) * (1.0f / (Dd - 1));
    var = fmaxf(var, 0.0f);
    float g = gp[0], be = bp[0];
    float rs = g / (sqrtf(var) + EPSf);
    bf16* q = lnout + (size_t)row * Dd + tid * 4;
#pragma unroll
    for (int i = 0; i < 4; i++) q[i] = (bf16)((v[i] - mean) * rs + be);
    return;
  }
  // ---------------- weight transpose ----------------
  __shared__ float t[64 * 65];
  const float* in;
  bf16* out;
  int R, C, local, sh;
  if (bi < 1024) {
    const int j = bi >> 8;
    local = bi & 255; R = 1024; C = 1024; sh = 4;
    in = (j == 0) ? i0 : (j == 1) ? i1 : (j == 2) ? i2 : i3;
    out = (j == 0) ? o0 : (j == 1) ? o1 : (j == 2) ? o2 : o3;
  } else if (bi < 2048) {
    local = bi - 1024; R = 1024; C = 4096; sh = 6; in = i4; out = o4;
  } else {
    local = bi - 2048; R = 4096; C = 1024; sh = 4; in = i5; out = o5;
  }
  const int nx = 1 << sh;
  const int bx = local & (nx - 1), by = local >> sh;
  const int tx = tid & 63, ty = tid >> 6;
  const int r0 = by * 64, c0 = bx * 64;
#pragma unroll
  for (int i = 0; i < 16; i++) {
    int r = ty + i * 4;
    t[r * 65 + tx] = in[(size_t)(r0 + r) * C + c0 + tx];
  }
  __syncthreads();
#pragma unroll
  for (int i = 0; i < 16; i++) {
    int r = ty + i * 4;
    out[(size_t)(c0 + r) * R + r0 + tx] = (bf16)t[tx * 65 + r];
  }
}

// =====================================================================
// LayerNorm (ddof=1, scalar gamma/beta, /(std+eps)). fp32 in, bf16 out.
// =====================================================================
__global__ __launch_bounds__(256) void ln_kernel(
    const float* __restrict__ in, bf16* __restrict__ out,
    const float* __restrict__ gp, const float* __restrict__ bp) {
  const int row = blockIdx.x;
  const int tid = threadIdx.x;
  float v[4];
  const float* p = in + (size_t)row * Dd + tid * 4;
#pragma unroll
  for (int i = 0; i < 4; i++) v[i] = p[i];
  float s = v[0] + v[1] + v[2] + v[3];
  float s2 = v[0] * v[0] + v[1] * v[1] + v[2] * v[2] + v[3] * v[3];
#pragma unroll
  for (int m = 1; m < 64; m <<= 1) {
    s += __shfl_xor(s, m, 64);
    s2 += __shfl_xor(s2, m, 64);
  }
  __shared__ float ls[4], ls2[4];
  if ((tid & 63) == 0) {
    ls[tid >> 6] = s;
    ls2[tid >> 6] = s2;
  }
  __syncthreads();
  s = ls[0] + ls[1] + ls[2] + ls[3];
  s2 = ls2[0] + ls2[1] + ls2[2] + ls2[3];
  float mean = s * (1.0f / Dd);
  float var = (s2 - (float)Dd * mean * mean) * (1.0f / (Dd - 1));
  var = fmaxf(var, 0.0f);
  float g = gp[0], be = bp[0];
  float rs = g / (sqrtf(var) + EPSf);
  bf16* q = out + (size_t)row * Dd + tid * 4;
#pragma unroll
  for (int i = 0; i < 4; i++) q[i] = (bf16)((v[i] - mean) * rs + be);
}

// =====================================================================
// GEMM C = A(M,K; stride sa) @ Bt(N,K; stride sb)^T + epilogue.
// 128x128 tile, templated BK, 4 waves, 4x4 MFMA 16x16x32, XOR swizzle.
// XCD-aware block remap (T1).
// EPI: 1 bias+resid(f32)->f32 | 2 bias,relu->bf16 | 3 resid(f32)->f32
//      4 qkv 3-way bias; Q,K -> bf16 Cout, V -> LDS-transposed
//        coalesced store into vtb (requires BK==64: T uses 32KB smem)
// =====================================================================
template <int EPI, int BK>
__global__ __launch_bounds__(256) void gemm_bt(
    const bf16* __restrict__ A, const bf16* __restrict__ Bt,
    const float* __restrict__ bias, const float* __restrict__ bias2,
    const float* __restrict__ bias3, const float* __restrict__ resid,
    bf16* __restrict__ vtb, void* __restrict__ Cout, int M, int N, int K,
    int sa, int sb) {
  __shared__ __attribute__((aligned(16))) char smem[2 * 128 * BK * 2];
  bf16* As = (bf16*)smem;
  bf16* Bs = (bf16*)(smem + 128 * BK * 2);
  constexpr int CPR = BK / 8;       // 8-elem chunks per row
  constexpr int RPJ = 256 / CPR;    // rows staged per j-iteration
  constexpr int NJ = BK / 16;       // j-iterations per operand
  const int tid = threadIdx.x;
  const int ln = tid & 63;
  const int wv = tid >> 6;
  const int wm = wv >> 1, wn = wv & 1;
  const int quad = ln >> 4, l16 = ln & 15;
  const int l7 = l16 & 7;
  // T1 XCD-aware remap (dispatch order is x-fastest; XCD ~ d % 8)
  const int nxg = gridDim.x;
  const int d = blockIdx.y * nxg + blockIdx.x;
  const int sseq = d >> 3;
  const int bxr = sseq % nxg;
  const int byr = (d & 7) + 8 * (sseq / nxg);
  const int m0 = byr * 128, n0 = bxr * 128;

  f32x4 acc[4][4];
#pragma unroll
  for (int i = 0; i < 4; i++)
#pragma unroll
    for (int j = 0; j < 4; j++) acc[i][j] = {0.f, 0.f, 0.f, 0.f};

  const int sr = tid / CPR;                    // staging row (within j-blk)
  const int sc = (tid & (CPR - 1)) ^ (sr & 7); // swizzled source chunk
  const size_t abase = (size_t)(m0 + sr) * sa + sc * 8;
  const size_t bbase = (size_t)(n0 + sr) * sb + sc * 8;

  for (int k0 = 0; k0 < K; k0 += BK) {
#pragma unroll
    for (int j = 0; j < NJ; j++) {
      gl_lds16(A + abase + (size_t)(j * RPJ) * sa + k0,
               (char*)As + j * 4096 + wv * 1024);
      gl_lds16(Bt + bbase + (size_t)(j * RPJ) * sb + k0,
               (char*)Bs + j * 4096 + wv * 1024);
    }
    __syncthreads();
#pragma unroll
    for (int kh = 0; kh < BK / 32; kh++) {
      bf16x8 af[4], bfr[4];
#pragma unroll
      for (int mi = 0; mi < 4; mi++)
        af[mi] = *(const bf16x8*)&As[(wm * 64 + mi * 16 + l16) * BK +
                                     ((kh * 4 + quad) ^ l7) * 8];
#pragma unroll
      for (int ni = 0; ni < 4; ni++)
        bfr[ni] = *(const bf16x8*)&Bs[(wn * 64 + ni * 16 + l16) * BK +
                                      ((kh * 4 + quad) ^ l7) * 8];
#pragma unroll
      for (int mi = 0; mi < 4; mi++)
#pragma unroll
        for (int ni = 0; ni < 4; ni++)
          acc[mi][ni] = __builtin_amdgcn_mfma_f32_16x16x32_bf16(
              af[mi], bfr[ni], acc[mi][ni], 0, 0, 0);
    }
    __syncthreads();
  }

  if constexpr (EPI == 4) {
    if (n0 < 2048) {  // Q,K -> qkv buffer (direct bf16 stores)
#pragma unroll
      for (int mi = 0; mi < 4; mi++) {
        const int m = m0 + wm * 64 + mi * 16 + quad * 4;
#pragma unroll
        for (int ni = 0; ni < 4; ni++) {
          const int n = n0 + wn * 64 + ni * 16 + l16;
          const float bvl = (n < 1024) ? bias[n] : bias2[n - 1024];
#pragma unroll
          for (int r = 0; r < 4; r++)
            ((bf16*)Cout)[(size_t)(m + r) * N + n] =
                (bf16)(acc[mi][ni][r] + bvl);
        }
      }
    } else {  // V: transpose 128x128 tile via LDS, coalesced store to vtb
      bf16* T = (bf16*)smem;  // [128][128] bf16 = 32 KB (BK must be 64)
#pragma unroll
      for (int mi = 0; mi < 4; mi++) {
        const int ml = wm * 64 + mi * 16 + quad * 4;  // local row, 4-contig
        const int c = ml >> 3, hf = (ml >> 2) & 1;
#pragma unroll
        for (int ni = 0; ni < 4; ni++) {
          const int nl = wn * 64 + ni * 16 + l16;  // local col
          const float bvl = bias3[(n0 - 2048) + nl];
          bf16x4 tv;
#pragma unroll
          for (int r = 0; r < 4; r++) tv[r] = (bf16)(acc[mi][ni][r] + bvl);
          *(bf16x4*)&T[nl * 128 + ((c ^ (nl & 15)) << 3) + (hf << 2)] = tv;
        }
      }
      __syncthreads();
      const size_t vbase =
          ((size_t)(m0 >> 10) * 1024 + (n0 - 2048)) * Ss + (m0 & 1023);
#pragma unroll
      for (int p = 0; p < 8; p++) {
        const int row = p * 16 + (tid >> 4);
        const int k = tid & 15;
        bf16x8 vv = *(const bf16x8*)&T[row * 128 + ((k ^ (row & 15)) << 3)];
        *(bf16x8*)&vtb[vbase + (size_t)row * Ss + k * 8] = vv;
      }
    }
  } else {
#pragma unroll
    for (int mi = 0; mi < 4; mi++) {
      const int m = m0 + wm * 64 + mi * 16 + quad * 4;
#pragma unroll
      for (int ni = 0; ni < 4; ni++) {
        const int n = n0 + wn * 64 + ni * 16 + l16;
        float bvl = 0.0f;
        if constexpr (EPI != 3) bvl = bias[n];
#pragma unroll
        for (int r = 0; r < 4; r++) {
          float val = acc[mi][ni][r] + bvl;
          const size_t idx = (size_t)(m + r) * N + n;
          if constexpr (EPI == 1) {
            ((float*)Cout)[idx] = val + resid[idx];
          } else if constexpr (EPI == 2) {
            ((bf16*)Cout)[idx] = (bf16)fmaxf(val, 0.0f);
          } else {
            ((float*)Cout)[idx] = val + resid[idx];
          }
        }
      }
    }
  }
}

// =====================================================================
// gemm256_relu v4: 4-phase, A-fragments fully register-resident.
// vs v3: phase-3 A0 re-read eliminated (af0/af1 both live, 24 instead
// of 32 ds_read_b128 per wave per K-tile, -25% LDS read traffic) and
// kh-outer MFMA order (8 independent accs between dependent reuses).
// Staging order B0B1/B2B3/A0A2/A1A3 with end-ph0 and end-ph3 vmcnt(2)
// -- identical wait contract to the verified v3 (trace re-checked:
// entering ph0 outstanding={A1,A3}; end-ph0 drains them before ph1's
// A1 reads; end-ph3 drains B0-3+A0,A2, leaves fresh A1,A3 flying).
// =====================================================================
__global__ __launch_bounds__(512) void gemm256_relu(
    const bf16* __restrict__ A, const bf16* __restrict__ Bt,
    const float* __restrict__ bias, bf16* __restrict__ Cout, int M, int N,
    int K, int sa, int sb) {
  __shared__ __attribute__((aligned(16))) char smem[131072];
  const int tid = threadIdx.x;
  const int ln = tid & 63;
  const int wv = tid >> 6;  // 0..7
  const int wm = wv >> 2, wn = wv & 3;
  const int quad = ln >> 4, l16 = ln & 15;
  const int l7 = l16 & 7;
  // T1 XCD-aware remap
  const int nxg = gridDim.x;
  const int d = blockIdx.y * nxg + blockIdx.x;
  const int sseq = d >> 3;
  const int bxr = sseq % nxg;
  const int byr = (d & 7) + 8 * (sseq / nxg);
  const int m0 = byr * 256, n0 = bxr * 256;

  f32x4 acc[8][4];
#pragma unroll
  for (int i = 0; i < 8; i++)
#pragma unroll
    for (int j = 0; j < 4; j++) acc[i][j] = {0.f, 0.f, 0.f, 0.f};

  const int sr = tid >> 3;              // staging row 0..63 (per chunk)
  const int sc = (tid & 7) ^ (sr & 7);  // swizzled source chunk
  const size_t abase = (size_t)(m0 + sr) * sa + sc * 8;
  const size_t bbase = (size_t)(n0 + sr) * sb + sc * 8;
  const int w8 = tid >> 6;  // wave-uniform LDS sub-base

  const int nt = K >> 6;
  int cur = 0;

  // prologue: stage tile 0 into buffer 0, full drain once
  {
#pragma unroll
    for (int j = 0; j < 4; j++) {
      gl_lds16(A + abase + (size_t)(j * 64) * sa,
               smem + j * 8192 + w8 * 1024);
      gl_lds16(Bt + bbase + (size_t)(j * 64) * sb,
               smem + 32768 + j * 8192 + w8 * 1024);
    }
  }
  asm volatile("s_waitcnt vmcnt(0)" ::: "memory");
  __builtin_amdgcn_s_barrier();

  for (int t = 0; t < nt; ++t) {
    const bf16* As = (const bf16*)(smem + cur * 65536);
    const bf16* Bs = (const bf16*)(smem + cur * 65536 + 32768);
    char* ldst = smem + (cur ^ 1) * 65536;
    const bool pf = (t + 1 < nt);
    const int koff = (t + 1) * 64;

    bf16x8 af0[4][2], af1[4][2], bfr[2][2];

    // -------- phase 0: read A(mh0)+B(nq0); stage B chunks 0,1 --------
#pragma unroll
    for (int mf = 0; mf < 4; mf++)
#pragma unroll
      for (int kh = 0; kh < 2; kh++)
        af0[mf][kh] = *(const bf16x8*)&As[(wm * 128 + mf * 16 + l16) * 64 +
                                          (((kh * 4 + quad) ^ l7) * 8)];
#pragma unroll
    for (int nf = 0; nf < 2; nf++)
#pragma unroll
      for (int kh = 0; kh < 2; kh++)
        bfr[nf][kh] = *(const bf16x8*)&Bs[(wn * 64 + nf * 16 + l16) * 64 +
                                          (((kh * 4 + quad) ^ l7) * 8)];
    if (pf) {
      gl_lds16(Bt + bbase + koff, ldst + 32768 + w8 * 1024);
      gl_lds16(Bt + bbase + (size_t)64 * sb + koff,
               ldst + 32768 + 8192 + w8 * 1024);
    }
    __builtin_amdgcn_s_barrier();
    __builtin_amdgcn_s_setprio(1);
#pragma unroll
    for (int kh = 0; kh < 2; kh++)
#pragma unroll
      for (int mf = 0; mf < 4; mf++)
#pragma unroll
        for (int nf = 0; nf < 2; nf++)
          acc[mf][nf] = __builtin_amdgcn_mfma_f32_16x16x32_bf16(
              af0[mf][kh], bfr[nf][kh], acc[mf][nf], 0, 0, 0);
    __builtin_amdgcn_s_setprio(0);
    // prev tile's A chunks 1,3 must land before ph1 reads them
    if (pf) {
      asm volatile("s_waitcnt vmcnt(2)" ::: "memory");
    } else {
      asm volatile("s_waitcnt vmcnt(0)" ::: "memory");
    }
    __builtin_amdgcn_s_barrier();

    // -------- phase 1: read A(mh1); stage B chunks 2,3 --------
#pragma unroll
    for (int mf = 0; mf < 4; mf++)
#pragma unroll
      for (int kh = 0; kh < 2; kh++)
        af1[mf][kh] =
            *(const bf16x8*)&As[(wm * 128 + 64 + mf * 16 + l16) * 64 +
                                (((kh * 4 + quad) ^ l7) * 8)];
    if (pf) {
      gl_lds16(Bt + bbase + (size_t)128 * sb + koff,
               ldst + 32768 + 16384 + w8 * 1024);
      gl_lds16(Bt + bbase + (size_t)192 * sb + koff,
               ldst + 32768 + 24576 + w8 * 1024);
    }
    __builtin_amdgcn_s_barrier();
    __builtin_amdgcn_s_setprio(1);
#pragma unroll
    for (int kh = 0; kh < 2; kh++)
#pragma unroll
      for (int mf = 0; mf < 4; mf++)
#pragma unroll
        for (int nf = 0; nf < 2; nf++)
          acc[4 + mf][nf] = __builtin_amdgcn_mfma_f32_16x16x32_bf16(
              af1[mf][kh], bfr[nf][kh], acc[4 + mf][nf], 0, 0, 0);
    __builtin_amdgcn_s_setprio(0);
    __builtin_amdgcn_s_barrier();

    // -------- phase 2: read B(nq1); stage A chunks 0,2 --------
#pragma unroll
    for (int nf = 0; nf < 2; nf++)
#pragma unroll
      for (int kh = 0; kh < 2; kh++)
        bfr[nf][kh] =
            *(const bf16x8*)&Bs[(wn * 64 + 32 + nf * 16 + l16) * 64 +
                                (((kh * 4 + quad) ^ l7) * 8)];
    if (pf) {
      gl_lds16(A + abase + koff, ldst + w8 * 1024);
      gl_lds16(A + abase + (size_t)128 * sa + koff,
               ldst + 16384 + w8 * 1024);
    }
    __builtin_amdgcn_s_barrier();
    __builtin_amdgcn_s_setprio(1);
#pragma unroll
    for (int kh = 0; kh < 2; kh++)
#pragma unroll
      for (int mf = 0; mf < 4; mf++)
#pragma unroll
        for (int nf = 0; nf < 2; nf++)
          acc[4 + mf][2 + nf] = __builtin_amdgcn_mfma_f32_16x16x32_bf16(
              af1[mf][kh], bfr[nf][kh], acc[4 + mf][2 + nf], 0, 0, 0);
    __builtin_amdgcn_s_setprio(0);
    __builtin_amdgcn_s_barrier();

    // -------- phase 3: NO ds_reads (af0 live); stage A chunks 1,3 ----
    if (pf) {
      gl_lds16(A + abase + (size_t)64 * sa + koff, ldst + 8192 + w8 * 1024);
      gl_lds16(A + abase + (size_t)192 * sa + koff,
               ldst + 24576 + w8 * 1024);
    }
    __builtin_amdgcn_s_barrier();
    __builtin_amdgcn_s_setprio(1);
#pragma unroll
    for (int kh = 0; kh < 2; kh++)
#pragma unroll
      for (int mf = 0; mf < 4; mf++)
#pragma unroll
        for (int nf = 0; nf < 2; nf++)
          acc[mf][2 + nf] = __builtin_amdgcn_mfma_f32_16x16x32_bf16(
              af0[mf][kh], bfr[nf][kh], acc[mf][2 + nf], 0, 0, 0);
    __builtin_amdgcn_s_setprio(0);
    // boundary: everything except the fresh A1,A3 pair must be landed
    if (pf) {
      asm volatile("s_waitcnt vmcnt(2)" ::: "memory");
    } else {
      asm volatile("s_waitcnt vmcnt(0)" ::: "memory");
    }
    __builtin_amdgcn_s_barrier();
    cur ^= 1;
  }

  // epilogue: bias + relu -> bf16
#pragma unroll
  for (int mi = 0; mi < 8; mi++) {
    const int m = m0 + wm * 128 + mi * 16 + quad * 4;
#pragma unroll
    for (int ni = 0; ni < 4; ni++) {
      const int n = n0 + wn * 64 + ni * 16 + l16;
      const float bvl = bias[n];
#pragma unroll
      for (int r = 0; r < 4; r++)
        Cout[(size_t)(m + r) * N + n] =
            (bf16)fmaxf(acc[mi][ni][r] + bvl, 0.0f);
    }
  }
}

// =====================================================================
// Flash attention v2: swapped QK^T (S^T = K·Q^T) on 32x32x16 MFMA.
// =====================================================================
__global__ __launch_bounds__(256) void attn_k(
    const bf16* __restrict__ qkv, const bf16* __restrict__ vt,
    const int* __restrict__ mask, bf16* __restrict__ ctx) {
  __shared__ __attribute__((aligned(16))) char smem[36864];
  __shared__ int Ft[16];
  bf16* Qs = (bf16*)smem;              // 16 KB (epilogue: transpose buf)
  bf16* Ks = (bf16*)(smem + 16384);    // 8 KB
  bf16* Vs = (bf16*)(smem + 24576);    // 8 KB
  float* Fm = (float*)(smem + 32768);  // 4 KB
  const int tid = threadIdx.x;
  const int l = tid & 63, w = tid >> 6;
  const int lq = l & 31, lh = l >> 5;
  const int lq7 = lq & 7;
  const int bh = blockIdx.x;
  const int b = bh >> 4, h = bh & 15;
  const int q0 = blockIdx.y * 128;
  const int sr = tid >> 3;              // staging row 0..31
  const int sc = (tid & 7) ^ (sr & 7);  // swizzled source chunk

  if (tid < 16) Ft[tid] = 0;
  {  // stage Q tile: 128 rows x 64 cols (async)
#pragma unroll
    for (int j = 0; j < 4; j++) {
      const size_t ga =
          (size_t)(b * Ss + q0 + j * 32 + sr) * 3072 + h * 64 + sc * 8;
      gl_lds16(qkv + ga, (char*)Qs + j * 4096 + w * 1024);
    }
  }
  __syncthreads();  // Ft init visible; Q staged (vmcnt drained)

  // Q B-fragments: col q = w*32+lq, k-elems d = s*16 + 8*lh + 0..7
  bf16x8 qf[4];
#pragma unroll
  for (int s = 0; s < 4; s++)
    qf[s] =
        *(const bf16x8*)&Qs[(w * 32 + lq) * 64 + (((s * 2 + lh) ^ lq7) * 8)];

  {  // mask -> additive log2-domain bias (0 or -inf) + per-tile flags
    const int4 mv = *(const int4*)&mask[b * Ss + tid * 4];
    const float ninf = -__builtin_inff();
    Fm[tid * 4 + 0] = mv.x ? 0.0f : ninf;
    Fm[tid * 4 + 1] = mv.y ? 0.0f : ninf;
    Fm[tid * 4 + 2] = mv.z ? 0.0f : ninf;
    Fm[tid * 4 + 3] = mv.w ? 0.0f : ninf;
    if (!(mv.x && mv.y && mv.z && mv.w)) atomicOr(&Ft[tid >> 4], 1);
  }

  f32x16 oacc[2];
#pragma unroll
  for (int d = 0; d < 2; d++)
#pragma unroll
    for (int r = 0; r < 16; r++) oacc[d][r] = 0.0f;
  float rsum = 0.0f;

  for (int kk0 = 0; kk0 < Ss; kk0 += 64) {
    {  // stage K (64 keys x 64 d) and Vt (64 d x 64 keys)
#pragma unroll
      for (int j = 0; j < 2; j++) {
        const size_t ga = (size_t)(b * Ss + kk0 + j * 32 + sr) * 3072 + 1024 +
                          h * 64 + sc * 8;
        gl_lds16(qkv + ga, (char*)Ks + j * 4096 + w * 1024);
        const size_t gv = (size_t)(bh * 64 + j * 32 + sr) * Ss + kk0 + sc * 8;
        gl_lds16(vt + gv, (char*)Vs + j * 4096 + w * 1024);
      }
    }
    __syncthreads();  // K/V ready; Fm/Ft visible (first iter)

    // S^T[key][q]: A = K rows (keys), B = Q cols (q). C: col=lane&31=q,
    // row(key) = (reg&3) + 8*(reg>>2) + 4*(lane>>5).
    f32x16 sacc[2];
#pragma unroll
    for (int kb = 0; kb < 2; kb++)
#pragma unroll
      for (int r = 0; r < 16; r++) sacc[kb][r] = 0.0f;

    __builtin_amdgcn_s_setprio(1);
#pragma unroll
    for (int kb = 0; kb < 2; kb++)
#pragma unroll
      for (int s = 0; s < 4; s++) {
        const bf16x8 kf = *(const bf16x8*)&Ks[(kb * 32 + lq) * 64 +
                                              (((s * 2 + lh) ^ lq7) * 8)];
        sacc[kb] = __builtin_amdgcn_mfma_f32_32x32x16_bf16(kf, qf[s],
                                                           sacc[kb], 0, 0, 0);
      }
    __builtin_amdgcn_s_setprio(0);

    if (__builtin_amdgcn_readfirstlane(Ft[kk0 >> 6])) {
      // slow path: additive mask per key
#pragma unroll
      for (int kb = 0; kb < 2; kb++)
#pragma unroll
        for (int g = 0; g < 4; g++) {
          const f32x4 mv = *(const f32x4*)&Fm[kk0 + kb * 32 + 4 * lh + 8 * g];
#pragma unroll
          for (int j = 0; j < 4; j++)
            sacc[kb][g * 4 + j] = __builtin_amdgcn_exp2f(
                fmaf(sacc[kb][g * 4 + j], SM_SCALE, mv[j]));
        }
    } else {
#pragma unroll
      for (int kb = 0; kb < 2; kb++)
#pragma unroll
        for (int r = 0; r < 16; r++)
          sacc[kb][r] = __builtin_amdgcn_exp2f(sacc[kb][r] * SM_SCALE);
    }
    // rowsum (balanced tree; cross-half combined after the loop)
#pragma unroll
    for (int kb = 0; kb < 2; kb++) {
      const float t0 = (sacc[kb][0] + sacc[kb][1]) + (sacc[kb][2] + sacc[kb][3]);
      const float t1 = (sacc[kb][4] + sacc[kb][5]) + (sacc[kb][6] + sacc[kb][7]);
      const float t2 =
          (sacc[kb][8] + sacc[kb][9]) + (sacc[kb][10] + sacc[kb][11]);
      const float t3 =
          (sacc[kb][12] + sacc[kb][13]) + (sacc[kb][14] + sacc[kb][15]);
      rsum += ((t0 + t1) + (t2 + t3));
    }

    // pack P^T to bf16 B-frags in-register and run PV on the fly
    __builtin_amdgcn_s_setprio(1);
#pragma unroll
    for (int t = 0; t < 4; t++) {
      const int kb = t >> 1, rb = (t & 1) * 8;
      u32 pa = cvtpk(sacc[kb][rb + 0], sacc[kb][rb + 1]);  // keys {0,1}+4lh
      u32 pbv = cvtpk(sacc[kb][rb + 2], sacc[kb][rb + 3]); // keys {2,3}+4lh
      u32 pc = cvtpk(sacc[kb][rb + 4], sacc[kb][rb + 5]);  // keys {8,9}+4lh
      u32 pd = cvtpk(sacc[kb][rb + 6], sacc[kb][rb + 7]);  // keys {10,11}+4lh
      // swap upper half of first with lower half of second:
      // pa -> [a_lo|c_lo] (word0), pc -> [a_hi|c_hi] (word2)
      asm("v_permlane32_swap_b32 %0, %1" : "+v"(pa), "+v"(pc));
      asm("v_permlane32_swap_b32 %0, %1" : "+v"(pbv), "+v"(pd));
      union {
        u32 u[4];
        bf16x8 v;
      } pk;
      pk.u[0] = pa;
      pk.u[1] = pbv;
      pk.u[2] = pc;
      pk.u[3] = pd;
      const int vsw = ((t * 2 + lh) ^ lq7) * 8;
      const bf16x8 vf0 = *(const bf16x8*)&Vs[lq * 64 + vsw];
      const bf16x8 vf1 = *(const bf16x8*)&Vs[(32 + lq) * 64 + vsw];
      oacc[0] =
          __builtin_amdgcn_mfma_f32_32x32x16_bf16(vf0, pk.v, oacc[0], 0, 0, 0);
      oacc[1] =
          __builtin_amdgcn_mfma_f32_32x32x16_bf16(vf1, pk.v, oacc[1], 0, 0, 0);
    }
    __builtin_amdgcn_s_setprio(0);
    __syncthreads();
  }

  // combine the two lane-halves' partial rowsums (semantics-invariant)
  float xs = rsum, ys = rsum;
  asm("v_permlane32_swap_b32 %0, %1" : "+v"(xs), "+v"(ys));
  const float inv = 1.0f / (xs + ys);

  // epilogue: per-wave LDS transpose (stride 72 kills bank conflicts),
  // then coalesced 16B global stores. All smem dead after final barrier.
  bf16* Tb = (bf16*)(smem + w * 4608);  // 32 rows x 72 bf16 = 4608 B
#pragma unroll
  for (int dblk = 0; dblk < 2; dblk++)
#pragma unroll
    for (int g = 0; g < 4; g++) {
      const u32 lo =
          cvtpk(oacc[dblk][g * 4 + 0] * inv, oacc[dblk][g * 4 + 1] * inv);
      const u32 hi =
          cvtpk(oacc[dblk][g * 4 + 2] * inv, oacc[dblk][g * 4 + 3] * inv);
      u32x2 pr2;
      pr2[0] = lo;
      pr2[1] = hi;
      const int dbase = dblk * 32 + 8 * g + 4 * lh;
      *(u32x2*)&Tb[lq * 72 + dbase] = pr2;
    }
  __syncthreads();
#pragma unroll
  for (int p = 0; p < 4; p++) {
    const int row = p * 8 + (l >> 3);
    const int ch = l & 7;
    const bf16x8 vv = *(const bf16x8*)&Tb[row * 72 + ch * 8];
    *(bf16x8*)&ctx[(size_t)(b * Ss + q0 + w * 32 + row) * Dd + h * 64 +
                   ch * 8] = vv;
  }
}

// =====================================================================
extern "C" void kernel_launch(void* const* d_in, const int* in_sizes, int n_in,
                              void* d_out, int out_size, void* d_ws,
                              size_t ws_size, hipStream_t stream) {
  (void)in_sizes; (void)n_in; (void)out_size;
  const float* x = (const float*)d_in[0];
  const int* mask = (const int*)d_in[1];
  const float* wq = (const float*)d_in[2];
  const float* bq = (const float*)d_in[3];
  const float* wk = (const float*)d_in[4];
  const float* bk = (const float*)d_in[5];
  const float* wvw = (const float*)d_in[6];
  const float* bv = (const float*)d_in[7];
  const float* wo = (const float*)d_in[8];
  const float* bo = (const float*)d_in[9];
  const float* w1 = (const float*)d_in[10];
  const float* b1 = (const float*)d_in[11];
  const float* w2 = (const float*)d_in[12];
  const float* b2 = (const float*)d_in[13];
  const float* g1 = (const float*)d_in[14];
  const float* be1 = (const float*)d_in[15];
  const float* g2 = (const float*)d_in[16];
  const float* be2 = (const float*)d_in[17];
  float* out = (float*)d_out;

  char* ws = (char*)d_ws;
  const size_t MB = 1024 * 1024;
  bf16* w1T = (bf16*)(ws + 0 * MB);     // 8 MB  (4096x1024)
  bf16* w2T = (bf16*)(ws + 8 * MB);     // 8 MB  (1024x4096)
  bf16* wqkvT = (bf16*)(ws + 16 * MB);  // 6 MB  (3072x1024)
  bf16* woT = (bf16*)(ws + 22 * MB);    // 2 MB
  bf16* lnb = (bf16*)(ws + 24 * MB);    // 16 MB (ln1 -> ctx -> ln2)
  bf16* qkv = (bf16*)(ws + 40 * MB);    // 48 MB (8192x3072; V slots unused)
  bf16* vtb = (bf16*)(ws + 88 * MB);    // 16 MB
  float* x1 = (float*)(ws + 40 * MB);   // 32 MB overlay (qkv dead post-WO-in)
  bf16* ctx = lnb;                      // lnb dead after QKV GEMM

  dim3 blk(256);
  // fused: weight transposes + LN1 in one dispatch
  prep_k<<<3072 + 8192, blk, 0, stream>>>(
      wq, wk, wvw, wo, w1, w2, wqkvT, wqkvT + (size_t)1024 * 1024,
      wqkvT + (size_t)2048 * 1024, woT, w1T, w2T, x, lnb, g1, be1);
  // fused QKV projection; V transposed via LDS into vtb (coalesced)
  gemm_bt<4, 64><<<dim3(24, 64), blk, 0, stream>>>(
      lnb, wqkvT, bq, bk, bv, nullptr, vtb, qkv, 8192, 3072, 1024, 1024, 1024);
  // attention: grid (bh, qtile) -> q-tiles of one head share an XCD L2
  attn_k<<<dim3(128, 8), blk, 0, stream>>>(qkv, vtb, mask, ctx);
  // WO + bias + residual(x fp32) -> x1 (grid-capped 2 blk/CU -> BK=128)
  gemm_bt<1, 128><<<dim3(8, 64), blk, 0, stream>>>(
      ctx, woT, bo, nullptr, nullptr, x, nullptr, x1, 8192, 1024, 1024, 1024,
      1024);
  // LN2
  ln_kernel<<<8192, blk, 0, stream>>>(x1, lnb, g2, be2);

  if (ws_size >= 136 * MB) {
    // single-shot FFN: mid = 8192x4096 bf16 at 72..136 MB
    bf16* mid = (bf16*)(ws + 72 * MB);
    // FFN1 on the 256x256 4-phase counted-vmcnt pipeline
    gemm256_relu<<<dim3(16, 32), dim3(512), 0, stream>>>(
        lnb, w1T, b1, mid, 8192, 4096, 1024, 1024, 1024);
    gemm_bt<1, 128><<<dim3(8, 64), blk, 0, stream>>>(
        mid, w2T, b2, nullptr, nullptr, x1, nullptr, out, 8192, 1024, 4096,
        4096, 4096);
  } else {
    // chunked FFN (DFF=2048 halves), mid = 32 MB at 72..104 MB
    bf16* mid = (bf16*)(ws + 72 * MB);
    gemm256_relu<<<dim3(8, 32), dim3(512), 0, stream>>>(
        lnb, w1T, b1, mid, 8192, 2048, 1024, 1024, 1024);
    gemm_bt<1, 128><<<dim3(8, 64), blk, 0, stream>>>(
        mid, w2T, b2, nullptr, nullptr, x1, nullptr, out, 8192, 1024, 2048,
        2048, 4096);
    gemm256_relu<<<dim3(8, 32), dim3(512), 0, stream>>>(
        lnb, w1T + (size_t)2048 * 1024, b1 + 2048, mid, 8192, 2048, 1024,
        1024, 1024);
    gemm_bt<3, 128><<<dim3(8, 64), blk, 0, stream>>>(
        mid, w2T + 2048, nullptr, nullptr, nullptr, out, nullptr, out, 8192,
        1024, 2048, 2048, 4096);
  }
}

// Round 9
// 441.031 us; speedup vs baseline: 1.0299x; 1.0285x over previous
//
#include <hip/hip_runtime.h>
#include <math.h>

typedef __bf16 bf16;
typedef float f32x4 __attribute__((ext_vector_type(4)));
typedef float f32x16 __attribute__((ext_vector_type(16)));
typedef bf16 bf16x8 __attribute__((ext_vector_type(8)));
typedef bf16 bf16x4 __attribute__((ext_vector_type(4)));
typedef unsigned int u32;
typedef unsigned int u32x2 __attribute__((ext_vector_type(2)));

#define DEV __device__ __forceinline__

constexpr int Ss = 1024, Dd = 1024;
constexpr float EPSf = 1e-6f;
// softmax in log2 domain: scale = (1/sqrt(64)) * log2(e)
constexpr float SM_SCALE = 0.125f * 1.4426950408889634f;

// ---- async global->LDS, 16B per lane, wave-uniform LDS base ----
DEV void gl_lds16(const void* g, void* l) {
  __builtin_amdgcn_global_load_lds(
      (const __attribute__((address_space(1))) void*)g,
      (__attribute__((address_space(3))) void*)l, 16, 0, 0);
}

// pack 2 f32 -> 2 bf16 in one u32 (low = first arg)
DEV u32 cvtpk(float lo, float hi) {
  u32 r;
  asm("v_cvt_pk_bf16_f32 %0, %1, %2" : "=v"(r) : "v"(lo), "v"(hi));
  return r;
}

// =====================================================================
// Fused: six weight transposes (fp32 (K,N) -> bf16 (N,K)) + LN1.
// Blocks [0,3072) do transpose tiles; [3072, 3072+8192) do LN rows.
// =====================================================================
__global__ __launch_bounds__(256) void prep_k(
    const float* __restrict__ i0, const float* __restrict__ i1,
    const float* __restrict__ i2, const float* __restrict__ i3,
    const float* __restrict__ i4, const float* __restrict__ i5,
    bf16* __restrict__ o0, bf16* __restrict__ o1, bf16* __restrict__ o2,
    bf16* __restrict__ o3, bf16* __restrict__ o4, bf16* __restrict__ o5,
    const float* __restrict__ xin, bf16* __restrict__ lnout,
    const float* __restrict__ gp, const float* __restrict__ bp) {
  const int bi = blockIdx.x;
  const int tid = threadIdx.x;
  if (bi >= 3072) {
    // ---------------- LayerNorm (ddof=1, scalar gamma/beta) ----------
    const int row = bi - 3072;
    float v[4];
    const float* p = xin + (size_t)row * Dd + tid * 4;
#pragma unroll
    for (int i = 0; i < 4; i++) v[i] = p[i];
    float s = v[0] + v[1] + v[2] + v[3];
    float s2 = v[0] * v[0] + v[1] * v[1] + v[2] * v[2] + v[3] * v[3];
#pragma unroll
    for (int m = 1; m < 64; m <<= 1) {
      s += __shfl_xor(s, m, 64);
      s2 += __shfl_xor(s2, m, 64);
    }
    __shared__ float ls[4], ls2[4];
    if ((tid & 63) == 0) {
      ls[tid >> 6] = s;
      ls2[tid >> 6] = s2;
    }
    __syncthreads();
    s = ls[0] + ls[1] + ls[2] + ls[3];
    s2 = ls2[0] + ls2[1] + ls2[2] + ls2[3];
    float mean = s * (1.0f / Dd);
    float var = (s2 - (float)Dd * mean * mean) * (1.0f / (Dd - 1));
    var = fmaxf(var, 0.0f);
    float g = gp[0], be = bp[0];
    float rs = g / (sqrtf(var) + EPSf);
    bf16* q = lnout + (size_t)row * Dd + tid * 4;
#pragma unroll
    for (int i = 0; i < 4; i++) q[i] = (bf16)((v[i] - mean) * rs + be);
    return;
  }
  // ---------------- weight transpose ----------------
  __shared__ float t[64 * 65];
  const float* in;
  bf16* out;
  int R, C, local, sh;
  if (bi < 1024) {
    const int j = bi >> 8;
    local = bi & 255; R = 1024; C = 1024; sh = 4;
    in = (j == 0) ? i0 : (j == 1) ? i1 : (j == 2) ? i2 : i3;
    out = (j == 0) ? o0 : (j == 1) ? o1 : (j == 2) ? o2 : o3;
  } else if (bi < 2048) {
    local = bi - 1024; R = 1024; C = 4096; sh = 6; in = i4; out = o4;
  } else {
    local = bi - 2048; R = 4096; C = 1024; sh = 4; in = i5; out = o5;
  }
  const int nx = 1 << sh;
  const int bx = local & (nx - 1), by = local >> sh;
  const int tx = tid & 63, ty = tid >> 6;
  const int r0 = by * 64, c0 = bx * 64;
#pragma unroll
  for (int i = 0; i < 16; i++) {
    int r = ty + i * 4;
    t[r * 65 + tx] = in[(size_t)(r0 + r) * C + c0 + tx];
  }
  __syncthreads();
#pragma unroll
  for (int i = 0; i < 16; i++) {
    int r = ty + i * 4;
    out[(size_t)(c0 + r) * R + r0 + tx] = (bf16)t[tx * 65 + r];
  }
}

// =====================================================================
// LayerNorm reading bf16 input (x1 residual stream), bf16 out.
// =====================================================================
__global__ __launch_bounds__(256) void ln_bf16_k(
    const bf16* __restrict__ in, bf16* __restrict__ out,
    const float* __restrict__ gp, const float* __restrict__ bp) {
  const int row = blockIdx.x;
  const int tid = threadIdx.x;
  const bf16x4 vv = *(const bf16x4*)(in + (size_t)row * Dd + tid * 4);
  float v[4];
#pragma unroll
  for (int i = 0; i < 4; i++) v[i] = (float)vv[i];
  float s = v[0] + v[1] + v[2] + v[3];
  float s2 = v[0] * v[0] + v[1] * v[1] + v[2] * v[2] + v[3] * v[3];
#pragma unroll
  for (int m = 1; m < 64; m <<= 1) {
    s += __shfl_xor(s, m, 64);
    s2 += __shfl_xor(s2, m, 64);
  }
  __shared__ float ls[4], ls2[4];
  if ((tid & 63) == 0) {
    ls[tid >> 6] = s;
    ls2[tid >> 6] = s2;
  }
  __syncthreads();
  s = ls[0] + ls[1] + ls[2] + ls[3];
  s2 = ls2[0] + ls2[1] + ls2[2] + ls2[3];
  float mean = s * (1.0f / Dd);
  float var = (s2 - (float)Dd * mean * mean) * (1.0f / (Dd - 1));
  var = fmaxf(var, 0.0f);
  float g = gp[0], be = bp[0];
  float rs = g / (sqrtf(var) + EPSf);
  bf16* q = out + (size_t)row * Dd + tid * 4;
#pragma unroll
  for (int i = 0; i < 4; i++) q[i] = (bf16)((v[i] - mean) * rs + be);
}

// =====================================================================
// GEMM C = A(M,K; stride sa) @ Bt(N,K; stride sb)^T + epilogue.
// 128x128 tile, templated BK, 4 waves, 4x4 MFMA 16x16x32, XOR swizzle.
// XCD-aware block remap (T1).
// EPI: 1 bias+resid(f32)->f32 | 2 bias,relu->bf16 | 3 resid(f32)->f32
//      4 qkv 3-way bias; Q,K -> bf16 Cout, V -> LDS-transposed vtb
//      5 bias+resid(f32)->bf16 (WO: residual stream to bf16)
//      6 bias+resid(bf16, passed via vtb)->f32 (FFN2)
// =====================================================================
template <int EPI, int BK>
__global__ __launch_bounds__(256) void gemm_bt(
    const bf16* __restrict__ A, const bf16* __restrict__ Bt,
    const float* __restrict__ bias, const float* __restrict__ bias2,
    const float* __restrict__ bias3, const float* __restrict__ resid,
    const bf16* __restrict__ vtbr, bf16* __restrict__ vtb,
    void* __restrict__ Cout, int M, int N, int K, int sa, int sb) {
  __shared__ __attribute__((aligned(16))) char smem[2 * 128 * BK * 2];
  bf16* As = (bf16*)smem;
  bf16* Bs = (bf16*)(smem + 128 * BK * 2);
  constexpr int CPR = BK / 8;       // 8-elem chunks per row
  constexpr int RPJ = 256 / CPR;    // rows staged per j-iteration
  constexpr int NJ = BK / 16;       // j-iterations per operand
  const int tid = threadIdx.x;
  const int ln = tid & 63;
  const int wv = tid >> 6;
  const int wm = wv >> 1, wn = wv & 1;
  const int quad = ln >> 4, l16 = ln & 15;
  const int l7 = l16 & 7;
  // T1 XCD-aware remap (dispatch order is x-fastest; XCD ~ d % 8)
  const int nxg = gridDim.x;
  const int d = blockIdx.y * nxg + blockIdx.x;
  const int sseq = d >> 3;
  const int bxr = sseq % nxg;
  const int byr = (d & 7) + 8 * (sseq / nxg);
  const int m0 = byr * 128, n0 = bxr * 128;

  f32x4 acc[4][4];
#pragma unroll
  for (int i = 0; i < 4; i++)
#pragma unroll
    for (int j = 0; j < 4; j++) acc[i][j] = {0.f, 0.f, 0.f, 0.f};

  const int sr = tid / CPR;                    // staging row (within j-blk)
  const int sc = (tid & (CPR - 1)) ^ (sr & 7); // swizzled source chunk
  const size_t abase = (size_t)(m0 + sr) * sa + sc * 8;
  const size_t bbase = (size_t)(n0 + sr) * sb + sc * 8;

  for (int k0 = 0; k0 < K; k0 += BK) {
#pragma unroll
    for (int j = 0; j < NJ; j++) {
      gl_lds16(A + abase + (size_t)(j * RPJ) * sa + k0,
               (char*)As + j * 4096 + wv * 1024);
      gl_lds16(Bt + bbase + (size_t)(j * RPJ) * sb + k0,
               (char*)Bs + j * 4096 + wv * 1024);
    }
    __syncthreads();
#pragma unroll
    for (int kh = 0; kh < BK / 32; kh++) {
      bf16x8 af[4], bfr[4];
#pragma unroll
      for (int mi = 0; mi < 4; mi++)
        af[mi] = *(const bf16x8*)&As[(wm * 64 + mi * 16 + l16) * BK +
                                     ((kh * 4 + quad) ^ l7) * 8];
#pragma unroll
      for (int ni = 0; ni < 4; ni++)
        bfr[ni] = *(const bf16x8*)&Bs[(wn * 64 + ni * 16 + l16) * BK +
                                      ((kh * 4 + quad) ^ l7) * 8];
#pragma unroll
      for (int mi = 0; mi < 4; mi++)
#pragma unroll
        for (int ni = 0; ni < 4; ni++)
          acc[mi][ni] = __builtin_amdgcn_mfma_f32_16x16x32_bf16(
              af[mi], bfr[ni], acc[mi][ni], 0, 0, 0);
    }
    __syncthreads();
  }

  if constexpr (EPI == 4) {
    if (n0 < 2048) {  // Q,K -> qkv buffer (direct bf16 stores)
#pragma unroll
      for (int mi = 0; mi < 4; mi++) {
        const int m = m0 + wm * 64 + mi * 16 + quad * 4;
#pragma unroll
        for (int ni = 0; ni < 4; ni++) {
          const int n = n0 + wn * 64 + ni * 16 + l16;
          const float bvl = (n < 1024) ? bias[n] : bias2[n - 1024];
#pragma unroll
          for (int r = 0; r < 4; r++)
            ((bf16*)Cout)[(size_t)(m + r) * N + n] =
                (bf16)(acc[mi][ni][r] + bvl);
        }
      }
    } else {  // V: transpose 128x128 tile via LDS, coalesced store to vtb
      bf16* T = (bf16*)smem;  // [128][128] bf16 = 32 KB (BK must be 64)
#pragma unroll
      for (int mi = 0; mi < 4; mi++) {
        const int ml = wm * 64 + mi * 16 + quad * 4;  // local row, 4-contig
        const int c = ml >> 3, hf = (ml >> 2) & 1;
#pragma unroll
        for (int ni = 0; ni < 4; ni++) {
          const int nl = wn * 64 + ni * 16 + l16;  // local col
          const float bvl = bias3[(n0 - 2048) + nl];
          bf16x4 tv;
#pragma unroll
          for (int r = 0; r < 4; r++) tv[r] = (bf16)(acc[mi][ni][r] + bvl);
          *(bf16x4*)&T[nl * 128 + ((c ^ (nl & 15)) << 3) + (hf << 2)] = tv;
        }
      }
      __syncthreads();
      const size_t vbase =
          ((size_t)(m0 >> 10) * 1024 + (n0 - 2048)) * Ss + (m0 & 1023);
#pragma unroll
      for (int p = 0; p < 8; p++) {
        const int row = p * 16 + (tid >> 4);
        const int k = tid & 15;
        bf16x8 vv = *(const bf16x8*)&T[row * 128 + ((k ^ (row & 15)) << 3)];
        *(bf16x8*)&vtb[vbase + (size_t)row * Ss + k * 8] = vv;
      }
    }
  } else {
#pragma unroll
    for (int mi = 0; mi < 4; mi++) {
      const int m = m0 + wm * 64 + mi * 16 + quad * 4;
#pragma unroll
      for (int ni = 0; ni < 4; ni++) {
        const int n = n0 + wn * 64 + ni * 16 + l16;
        float bvl = 0.0f;
        if constexpr (EPI != 3) bvl = bias[n];
#pragma unroll
        for (int r = 0; r < 4; r++) {
          float val = acc[mi][ni][r] + bvl;
          const size_t idx = (size_t)(m + r) * N + n;
          if constexpr (EPI == 1) {
            ((float*)Cout)[idx] = val + resid[idx];
          } else if constexpr (EPI == 2) {
            ((bf16*)Cout)[idx] = (bf16)fmaxf(val, 0.0f);
          } else if constexpr (EPI == 3) {
            ((float*)Cout)[idx] = val + resid[idx];
          } else if constexpr (EPI == 5) {
            ((bf16*)Cout)[idx] = (bf16)(val + resid[idx]);
          } else {  // EPI == 6
            ((float*)Cout)[idx] = val + (float)vtbr[idx];
          }
        }
      }
    }
  }
}

// =====================================================================
// gemm256_relu v4: 4-phase, A-fragments register-resident (FFN1).
// =====================================================================
__global__ __launch_bounds__(512) void gemm256_relu(
    const bf16* __restrict__ A, const bf16* __restrict__ Bt,
    const float* __restrict__ bias, bf16* __restrict__ Cout, int M, int N,
    int K, int sa, int sb) {
  __shared__ __attribute__((aligned(16))) char smem[131072];
  const int tid = threadIdx.x;
  const int ln = tid & 63;
  const int wv = tid >> 6;  // 0..7
  const int wm = wv >> 2, wn = wv & 3;
  const int quad = ln >> 4, l16 = ln & 15;
  const int l7 = l16 & 7;
  // T1 XCD-aware remap
  const int nxg = gridDim.x;
  const int d = blockIdx.y * nxg + blockIdx.x;
  const int sseq = d >> 3;
  const int bxr = sseq % nxg;
  const int byr = (d & 7) + 8 * (sseq / nxg);
  const int m0 = byr * 256, n0 = bxr * 256;

  f32x4 acc[8][4];
#pragma unroll
  for (int i = 0; i < 8; i++)
#pragma unroll
    for (int j = 0; j < 4; j++) acc[i][j] = {0.f, 0.f, 0.f, 0.f};

  const int sr = tid >> 3;              // staging row 0..63 (per chunk)
  const int sc = (tid & 7) ^ (sr & 7);  // swizzled source chunk
  const size_t abase = (size_t)(m0 + sr) * sa + sc * 8;
  const size_t bbase = (size_t)(n0 + sr) * sb + sc * 8;
  const int w8 = tid >> 6;  // wave-uniform LDS sub-base

  const int nt = K >> 6;
  int cur = 0;

  // prologue: stage tile 0 into buffer 0, full drain once
  {
#pragma unroll
    for (int j = 0; j < 4; j++) {
      gl_lds16(A + abase + (size_t)(j * 64) * sa,
               smem + j * 8192 + w8 * 1024);
      gl_lds16(Bt + bbase + (size_t)(j * 64) * sb,
               smem + 32768 + j * 8192 + w8 * 1024);
    }
  }
  asm volatile("s_waitcnt vmcnt(0)" ::: "memory");
  __builtin_amdgcn_s_barrier();

  for (int t = 0; t < nt; ++t) {
    const bf16* As = (const bf16*)(smem + cur * 65536);
    const bf16* Bs = (const bf16*)(smem + cur * 65536 + 32768);
    char* ldst = smem + (cur ^ 1) * 65536;
    const bool pf = (t + 1 < nt);
    const int koff = (t + 1) * 64;

    bf16x8 af0[4][2], af1[4][2], bfr[2][2];

    // -------- phase 0: read A(mh0)+B(nq0); stage B chunks 0,1 --------
#pragma unroll
    for (int mf = 0; mf < 4; mf++)
#pragma unroll
      for (int kh = 0; kh < 2; kh++)
        af0[mf][kh] = *(const bf16x8*)&As[(wm * 128 + mf * 16 + l16) * 64 +
                                          (((kh * 4 + quad) ^ l7) * 8)];
#pragma unroll
    for (int nf = 0; nf < 2; nf++)
#pragma unroll
      for (int kh = 0; kh < 2; kh++)
        bfr[nf][kh] = *(const bf16x8*)&Bs[(wn * 64 + nf * 16 + l16) * 64 +
                                          (((kh * 4 + quad) ^ l7) * 8)];
    if (pf) {
      gl_lds16(Bt + bbase + koff, ldst + 32768 + w8 * 1024);
      gl_lds16(Bt + bbase + (size_t)64 * sb + koff,
               ldst + 32768 + 8192 + w8 * 1024);
    }
    __builtin_amdgcn_s_barrier();
    __builtin_amdgcn_s_setprio(1);
#pragma unroll
    for (int kh = 0; kh < 2; kh++)
#pragma unroll
      for (int mf = 0; mf < 4; mf++)
#pragma unroll
        for (int nf = 0; nf < 2; nf++)
          acc[mf][nf] = __builtin_amdgcn_mfma_f32_16x16x32_bf16(
              af0[mf][kh], bfr[nf][kh], acc[mf][nf], 0, 0, 0);
    __builtin_amdgcn_s_setprio(0);
    // prev tile's A chunks 1,3 must land before ph1 reads them
    if (pf) {
      asm volatile("s_waitcnt vmcnt(2)" ::: "memory");
    } else {
      asm volatile("s_waitcnt vmcnt(0)" ::: "memory");
    }
    __builtin_amdgcn_s_barrier();

    // -------- phase 1: read A(mh1); stage B chunks 2,3 --------
#pragma unroll
    for (int mf = 0; mf < 4; mf++)
#pragma unroll
      for (int kh = 0; kh < 2; kh++)
        af1[mf][kh] =
            *(const bf16x8*)&As[(wm * 128 + 64 + mf * 16 + l16) * 64 +
                                (((kh * 4 + quad) ^ l7) * 8)];
    if (pf) {
      gl_lds16(Bt + bbase + (size_t)128 * sb + koff,
               ldst + 32768 + 16384 + w8 * 1024);
      gl_lds16(Bt + bbase + (size_t)192 * sb + koff,
               ldst + 32768 + 24576 + w8 * 1024);
    }
    __builtin_amdgcn_s_barrier();
    __builtin_amdgcn_s_setprio(1);
#pragma unroll
    for (int kh = 0; kh < 2; kh++)
#pragma unroll
      for (int mf = 0; mf < 4; mf++)
#pragma unroll
        for (int nf = 0; nf < 2; nf++)
          acc[4 + mf][nf] = __builtin_amdgcn_mfma_f32_16x16x32_bf16(
              af1[mf][kh], bfr[nf][kh], acc[4 + mf][nf], 0, 0, 0);
    __builtin_amdgcn_s_setprio(0);
    __builtin_amdgcn_s_barrier();

    // -------- phase 2: read B(nq1); stage A chunks 0,2 --------
#pragma unroll
    for (int nf = 0; nf < 2; nf++)
#pragma unroll
      for (int kh = 0; kh < 2; kh++)
        bfr[nf][kh] =
            *(const bf16x8*)&Bs[(wn * 64 + 32 + nf * 16 + l16) * 64 +
                                (((kh * 4 + quad) ^ l7) * 8)];
    if (pf) {
      gl_lds16(A + abase + koff, ldst + w8 * 1024);
      gl_lds16(A + abase + (size_t)128 * sa + koff,
               ldst + 16384 + w8 * 1024);
    }
    __builtin_amdgcn_s_barrier();
    __builtin_amdgcn_s_setprio(1);
#pragma unroll
    for (int kh = 0; kh < 2; kh++)
#pragma unroll
      for (int mf = 0; mf < 4; mf++)
#pragma unroll
        for (int nf = 0; nf < 2; nf++)
          acc[4 + mf][2 + nf] = __builtin_amdgcn_mfma_f32_16x16x32_bf16(
              af1[mf][kh], bfr[nf][kh], acc[4 + mf][2 + nf], 0, 0, 0);
    __builtin_amdgcn_s_setprio(0);
    __builtin_amdgcn_s_barrier();

    // -------- phase 3: NO ds_reads (af0 live); stage A chunks 1,3 ----
    if (pf) {
      gl_lds16(A + abase + (size_t)64 * sa + koff, ldst + 8192 + w8 * 1024);
      gl_lds16(A + abase + (size_t)192 * sa + koff,
               ldst + 24576 + w8 * 1024);
    }
    __builtin_amdgcn_s_barrier();
    __builtin_amdgcn_s_setprio(1);
#pragma unroll
    for (int kh = 0; kh < 2; kh++)
#pragma unroll
      for (int mf = 0; mf < 4; mf++)
#pragma unroll
        for (int nf = 0; nf < 2; nf++)
          acc[mf][2 + nf] = __builtin_amdgcn_mfma_f32_16x16x32_bf16(
              af0[mf][kh], bfr[nf][kh], acc[mf][2 + nf], 0, 0, 0);
    __builtin_amdgcn_s_setprio(0);
    // boundary: everything except the fresh A1,A3 pair must be landed
    if (pf) {
      asm volatile("s_waitcnt vmcnt(2)" ::: "memory");
    } else {
      asm volatile("s_waitcnt vmcnt(0)" ::: "memory");
    }
    __builtin_amdgcn_s_barrier();
    cur ^= 1;
  }

  // epilogue: bias + relu -> bf16
#pragma unroll
  for (int mi = 0; mi < 8; mi++) {
    const int m = m0 + wm * 128 + mi * 16 + quad * 4;
#pragma unroll
    for (int ni = 0; ni < 4; ni++) {
      const int n = n0 + wn * 64 + ni * 16 + l16;
      const float bvl = bias[n];
#pragma unroll
      for (int r = 0; r < 4; r++)
        Cout[(size_t)(m + r) * N + n] =
            (bf16)fmaxf(acc[mi][ni][r] + bvl, 0.0f);
    }
  }
}

// =====================================================================
// Flash attention v3: swapped QK^T on 32x32x16 MFMA + double-buffered
// K/V staging with counted vmcnt(4) (T3/T4). The Qs region (dead after
// Q-fragments go register-resident) hosts the second K/V buffer ->
// still 36 KB LDS, 4 blocks/CU. Tile t's K/V loads get a full
// iteration of flight instead of an immediate vmcnt(0) drain.
//   buf1: Ks [0,8K) Vs [8K,16K)   (overlays Qs; also epilogue Tb)
//   buf0: Ks [16K,24K) Vs [24K,32K)
//   Fm   [32K,36K)
// =====================================================================
__global__ __launch_bounds__(256) void attn_k(
    const bf16* __restrict__ qkv, const bf16* __restrict__ vt,
    const int* __restrict__ mask, bf16* __restrict__ ctx) {
  __shared__ __attribute__((aligned(16))) char smem[36864];
  __shared__ int Ft[16];
  bf16* Qs = (bf16*)smem;              // 16 KB (then buf1 / epi Tb)
  float* Fm = (float*)(smem + 32768);  // 4 KB
  const int tid = threadIdx.x;
  const int l = tid & 63, w = tid >> 6;
  const int lq = l & 31, lh = l >> 5;
  const int lq7 = lq & 7;
  const int bh = blockIdx.x;
  const int b = bh >> 4, h = bh & 15;
  const int q0 = blockIdx.y * 128;
  const int sr = tid >> 3;              // staging row 0..31
  const int sc = (tid & 7) ^ (sr & 7);  // swizzled source chunk

  if (tid < 16) Ft[tid] = 0;
  {  // stage Q tile (4 loads) + tile-0 K/V into buf0 (4 loads)
#pragma unroll
    for (int j = 0; j < 4; j++) {
      const size_t ga =
          (size_t)(b * Ss + q0 + j * 32 + sr) * 3072 + h * 64 + sc * 8;
      gl_lds16(qkv + ga, smem + j * 4096 + w * 1024);
    }
#pragma unroll
    for (int j = 0; j < 2; j++) {
      const size_t ga =
          (size_t)(b * Ss + j * 32 + sr) * 3072 + 1024 + h * 64 + sc * 8;
      gl_lds16(qkv + ga, smem + 16384 + j * 4096 + w * 1024);
      const size_t gv = (size_t)(bh * 64 + j * 32 + sr) * Ss + sc * 8;
      gl_lds16(vt + gv, smem + 24576 + j * 4096 + w * 1024);
    }
  }
  {  // mask -> additive log2-domain bias (0 or -inf) + per-tile flags
    const int4 mv = *(const int4*)&mask[b * Ss + tid * 4];
    const float ninf = -__builtin_inff();
    Fm[tid * 4 + 0] = mv.x ? 0.0f : ninf;
    Fm[tid * 4 + 1] = mv.y ? 0.0f : ninf;
    Fm[tid * 4 + 2] = mv.z ? 0.0f : ninf;
    Fm[tid * 4 + 3] = mv.w ? 0.0f : ninf;
    if (!(mv.x && mv.y && mv.z && mv.w)) atomicOr(&Ft[tid >> 4], 1);
  }
  __syncthreads();  // Q + tile0 K/V landed; Fm/Ft visible

  // Q B-fragments: col q = w*32+lq, k-elems d = s*16 + 8*lh + 0..7
  bf16x8 qf[4];
#pragma unroll
  for (int s = 0; s < 4; s++)
    qf[s] =
        *(const bf16x8*)&Qs[(w * 32 + lq) * 64 + (((s * 2 + lh) ^ lq7) * 8)];
  __syncthreads();  // all waves done reading Qs -> buf1 may overwrite

  f32x16 oacc[2];
#pragma unroll
  for (int d = 0; d < 2; d++)
#pragma unroll
    for (int r = 0; r < 16; r++) oacc[d][r] = 0.0f;
  float rsum = 0.0f;

  for (int t = 0; t < 16; ++t) {
    const int kk0 = t * 64;
    if (t + 1 < 16) {  // stage tile t+1 into the spare buffer
      char* dst = smem + (((t + 1) & 1) ? 0 : 16384);
      const int nk = kk0 + 64;
#pragma unroll
      for (int j = 0; j < 2; j++) {
        const size_t ga =
            (size_t)(b * Ss + nk + j * 32 + sr) * 3072 + 1024 + h * 64 +
            sc * 8;
        gl_lds16(qkv + ga, dst + j * 4096 + w * 1024);
        const size_t gv = (size_t)(bh * 64 + j * 32 + sr) * Ss + nk + sc * 8;
        gl_lds16(vt + gv, dst + 8192 + j * 4096 + w * 1024);
      }
      asm volatile("s_waitcnt vmcnt(4)" ::: "memory");  // tile t landed
    } else {
      asm volatile("s_waitcnt vmcnt(0)" ::: "memory");
    }
    __builtin_amdgcn_s_barrier();
    const bf16* Ks = (const bf16*)(smem + ((t & 1) ? 0 : 16384));
    const bf16* Vs = Ks + 4096;  // +8 KB

    // S^T[key][q]: A = K rows (keys), B = Q cols (q).
    f32x16 sacc[2];
#pragma unroll
    for (int kb = 0; kb < 2; kb++)
#pragma unroll
      for (int r = 0; r < 16; r++) sacc[kb][r] = 0.0f;

    __builtin_amdgcn_s_setprio(1);
#pragma unroll
    for (int kb = 0; kb < 2; kb++)
#pragma unroll
      for (int s = 0; s < 4; s++) {
        const bf16x8 kf = *(const bf16x8*)&Ks[(kb * 32 + lq) * 64 +
                                              (((s * 2 + lh) ^ lq7) * 8)];
        sacc[kb] = __builtin_amdgcn_mfma_f32_32x32x16_bf16(kf, qf[s],
                                                           sacc[kb], 0, 0, 0);
      }
    __builtin_amdgcn_s_setprio(0);

    if (__builtin_amdgcn_readfirstlane(Ft[t])) {
      // slow path: additive mask per key
#pragma unroll
      for (int kb = 0; kb < 2; kb++)
#pragma unroll
        for (int g = 0; g < 4; g++) {
          const f32x4 mv = *(const f32x4*)&Fm[kk0 + kb * 32 + 4 * lh + 8 * g];
#pragma unroll
          for (int j = 0; j < 4; j++)
            sacc[kb][g * 4 + j] = __builtin_amdgcn_exp2f(
                fmaf(sacc[kb][g * 4 + j], SM_SCALE, mv[j]));
        }
    } else {
#pragma unroll
      for (int kb = 0; kb < 2; kb++)
#pragma unroll
        for (int r = 0; r < 16; r++)
          sacc[kb][r] = __builtin_amdgcn_exp2f(sacc[kb][r] * SM_SCALE);
    }
    // rowsum (balanced tree; cross-half combined after the loop)
#pragma unroll
    for (int kb = 0; kb < 2; kb++) {
      const float t0 = (sacc[kb][0] + sacc[kb][1]) + (sacc[kb][2] + sacc[kb][3]);
      const float t1 = (sacc[kb][4] + sacc[kb][5]) + (sacc[kb][6] + sacc[kb][7]);
      const float t2 =
          (sacc[kb][8] + sacc[kb][9]) + (sacc[kb][10] + sacc[kb][11]);
      const float t3 =
          (sacc[kb][12] + sacc[kb][13]) + (sacc[kb][14] + sacc[kb][15]);
      rsum += ((t0 + t1) + (t2 + t3));
    }

    // pack P^T to bf16 B-frags in-register and run PV on the fly
    __builtin_amdgcn_s_setprio(1);
#pragma unroll
    for (int tt = 0; tt < 4; tt++) {
      const int kb = tt >> 1, rb = (tt & 1) * 8;
      u32 pa = cvtpk(sacc[kb][rb + 0], sacc[kb][rb + 1]);
      u32 pbv = cvtpk(sacc[kb][rb + 2], sacc[kb][rb + 3]);
      u32 pc = cvtpk(sacc[kb][rb + 4], sacc[kb][rb + 5]);
      u32 pd = cvtpk(sacc[kb][rb + 6], sacc[kb][rb + 7]);
      asm("v_permlane32_swap_b32 %0, %1" : "+v"(pa), "+v"(pc));
      asm("v_permlane32_swap_b32 %0, %1" : "+v"(pbv), "+v"(pd));
      union {
        u32 u[4];
        bf16x8 v;
      } pk;
      pk.u[0] = pa;
      pk.u[1] = pbv;
      pk.u[2] = pc;
      pk.u[3] = pd;
      const int vsw = ((tt * 2 + lh) ^ lq7) * 8;
      const bf16x8 vf0 = *(const bf16x8*)&Vs[lq * 64 + vsw];
      const bf16x8 vf1 = *(const bf16x8*)&Vs[(32 + lq) * 64 + vsw];
      oacc[0] =
          __builtin_amdgcn_mfma_f32_32x32x16_bf16(vf0, pk.v, oacc[0], 0, 0, 0);
      oacc[1] =
          __builtin_amdgcn_mfma_f32_32x32x16_bf16(vf1, pk.v, oacc[1], 0, 0, 0);
    }
    __builtin_amdgcn_s_setprio(0);
    asm volatile("s_waitcnt lgkmcnt(0)" ::: "memory");  // reads done
    __builtin_amdgcn_s_barrier();  // before buf(t&1) restaged at t+1
  }

  // combine the two lane-halves' partial rowsums (semantics-invariant)
  float xs = rsum, ys = rsum;
  asm("v_permlane32_swap_b32 %0, %1" : "+v"(xs), "+v"(ys));
  const float inv = 1.0f / (xs + ys);

  // epilogue: per-wave LDS transpose (stride 72), coalesced 16B stores.
  bf16* Tb = (bf16*)(smem + w * 4608);  // 32 rows x 72 bf16 = 4608 B
#pragma unroll
  for (int dblk = 0; dblk < 2; dblk++)
#pragma unroll
    for (int g = 0; g < 4; g++) {
      const u32 lo =
          cvtpk(oacc[dblk][g * 4 + 0] * inv, oacc[dblk][g * 4 + 1] * inv);
      const u32 hi =
          cvtpk(oacc[dblk][g * 4 + 2] * inv, oacc[dblk][g * 4 + 3] * inv);
      u32x2 pr2;
      pr2[0] = lo;
      pr2[1] = hi;
      const int dbase = dblk * 32 + 8 * g + 4 * lh;
      *(u32x2*)&Tb[lq * 72 + dbase] = pr2;
    }
  __syncthreads();
#pragma unroll
  for (int p = 0; p < 4; p++) {
    const int row = p * 8 + (l >> 3);
    const int ch = l & 7;
    const bf16x8 vv = *(const bf16x8*)&Tb[row * 72 + ch * 8];
    *(bf16x8*)&ctx[(size_t)(b * Ss + q0 + w * 32 + row) * Dd + h * 64 +
                   ch * 8] = vv;
  }
}

// =====================================================================
extern "C" void kernel_launch(void* const* d_in, const int* in_sizes, int n_in,
                              void* d_out, int out_size, void* d_ws,
                              size_t ws_size, hipStream_t stream) {
  (void)in_sizes; (void)n_in; (void)out_size;
  const float* x = (const float*)d_in[0];
  const int* mask = (const int*)d_in[1];
  const float* wq = (const float*)d_in[2];
  const float* bq = (const float*)d_in[3];
  const float* wk = (const float*)d_in[4];
  const float* bk = (const float*)d_in[5];
  const float* wvw = (const float*)d_in[6];
  const float* bv = (const float*)d_in[7];
  const float* wo = (const float*)d_in[8];
  const float* bo = (const float*)d_in[9];
  const float* w1 = (const float*)d_in[10];
  const float* b1 = (const float*)d_in[11];
  const float* w2 = (const float*)d_in[12];
  const float* b2 = (const float*)d_in[13];
  const float* g1 = (const float*)d_in[14];
  const float* be1 = (const float*)d_in[15];
  const float* g2 = (const float*)d_in[16];
  const float* be2 = (const float*)d_in[17];
  float* out = (float*)d_out;

  char* ws = (char*)d_ws;
  const size_t MB = 1024 * 1024;
  bf16* w1T = (bf16*)(ws + 0 * MB);     // 8 MB  (4096x1024)
  bf16* w2T = (bf16*)(ws + 8 * MB);     // 8 MB  (1024x4096)
  bf16* wqkvT = (bf16*)(ws + 16 * MB);  // 6 MB  (3072x1024)
  bf16* woT = (bf16*)(ws + 22 * MB);    // 2 MB
  bf16* lnb = (bf16*)(ws + 24 * MB);    // 16 MB (ln1 -> ctx -> ln2)
  bf16* qkv = (bf16*)(ws + 40 * MB);    // 48 MB (8192x3072; V slots unused)
  bf16* vtb = (bf16*)(ws + 88 * MB);    // 16 MB
  bf16* x1b = (bf16*)(ws + 40 * MB);    // 16 MB overlay (qkv dead post-WO-in)
  bf16* ctx = lnb;                      // lnb dead after QKV GEMM

  dim3 blk(256);
  // fused: weight transposes + LN1 in one dispatch
  prep_k<<<3072 + 8192, blk, 0, stream>>>(
      wq, wk, wvw, wo, w1, w2, wqkvT, wqkvT + (size_t)1024 * 1024,
      wqkvT + (size_t)2048 * 1024, woT, w1T, w2T, x, lnb, g1, be1);
  // fused QKV projection; V transposed via LDS into vtb (coalesced)
  gemm_bt<4, 64><<<dim3(24, 64), blk, 0, stream>>>(
      lnb, wqkvT, bq, bk, bv, nullptr, nullptr, vtb, qkv, 8192, 3072, 1024,
      1024, 1024);
  // attention: grid (bh, qtile) -> q-tiles of one head share an XCD L2
  attn_k<<<dim3(128, 8), blk, 0, stream>>>(qkv, vtb, mask, ctx);
  // WO + bias + residual(x fp32) -> x1 (bf16 residual stream)
  gemm_bt<5, 128><<<dim3(8, 64), blk, 0, stream>>>(
      ctx, woT, bo, nullptr, nullptr, x, nullptr, nullptr, x1b, 8192, 1024,
      1024, 1024, 1024);
  // LN2 (bf16 in)
  ln_bf16_k<<<8192, blk, 0, stream>>>(x1b, lnb, g2, be2);

  if (ws_size >= 136 * MB) {
    // single-shot FFN: mid = 8192x4096 bf16 at 72..136 MB
    bf16* mid = (bf16*)(ws + 72 * MB);
    gemm256_relu<<<dim3(16, 32), dim3(512), 0, stream>>>(
        lnb, w1T, b1, mid, 8192, 4096, 1024, 1024, 1024);
    // FFN2: bias + bf16 resid (x1b) -> f32 out
    gemm_bt<6, 128><<<dim3(8, 64), blk, 0, stream>>>(
        mid, w2T, b2, nullptr, nullptr, nullptr, x1b, nullptr, out, 8192,
        1024, 4096, 4096, 4096);
  } else {
    // chunked FFN (DFF=2048 halves), mid = 32 MB at 72..104 MB
    bf16* mid = (bf16*)(ws + 72 * MB);
    gemm256_relu<<<dim3(8, 32), dim3(512), 0, stream>>>(
        lnb, w1T, b1, mid, 8192, 2048, 1024, 1024, 1024);
    gemm_bt<6, 128><<<dim3(8, 64), blk, 0, stream>>>(
        mid, w2T, b2, nullptr, nullptr, nullptr, x1b, nullptr, out, 8192,
        1024, 2048, 2048, 4096);
    gemm256_relu<<<dim3(8, 32), dim3(512), 0, stream>>>(
        lnb, w1T + (size_t)2048 * 1024, b1 + 2048, mid, 8192, 2048, 1024,
        1024, 1024);
    gemm_bt<3, 128><<<dim3(8, 64), blk, 0, stream>>>(
        mid, w2T + 2048, nullptr, nullptr, nullptr, out, nullptr, nullptr,
        out, 8192, 1024, 2048, 2048, 4096);
  }
}

// Round 10
// 417.118 us; speedup vs baseline: 1.0889x; 1.0573x over previous
//
#include <hip/hip_runtime.h>
#include <math.h>

typedef __bf16 bf16;
typedef float f32x4 __attribute__((ext_vector_type(4)));
typedef float f32x16 __attribute__((ext_vector_type(16)));
typedef bf16 bf16x8 __attribute__((ext_vector_type(8)));
typedef bf16 bf16x4 __attribute__((ext_vector_type(4)));
typedef unsigned int u32;
typedef unsigned int u32x2 __attribute__((ext_vector_type(2)));

#define DEV __device__ __forceinline__

constexpr int Ss = 1024, Dd = 1024;
constexpr float EPSf = 1e-6f;
// softmax in log2 domain: scale = (1/sqrt(64)) * log2(e)
constexpr float SM_SCALE = 0.125f * 1.4426950408889634f;

// ---- async global->LDS, 16B per lane, wave-uniform LDS base ----
DEV void gl_lds16(const void* g, void* l) {
  __builtin_amdgcn_global_load_lds(
      (const __attribute__((address_space(1))) void*)g,
      (__attribute__((address_space(3))) void*)l, 16, 0, 0);
}

// pack 2 f32 -> 2 bf16 in one u32 (low = first arg)
DEV u32 cvtpk(float lo, float hi) {
  u32 r;
  asm("v_cvt_pk_bf16_f32 %0, %1, %2" : "=v"(r) : "v"(lo), "v"(hi));
  return r;
}

// =====================================================================
// Fused: six weight transposes (fp32 (K,N) -> bf16 (N,K)) + LN1.
// Blocks [0,3072) do transpose tiles; [3072, 3072+8192) do LN rows.
// =====================================================================
__global__ __launch_bounds__(256) void prep_k(
    const float* __restrict__ i0, const float* __restrict__ i1,
    const float* __restrict__ i2, const float* __restrict__ i3,
    const float* __restrict__ i4, const float* __restrict__ i5,
    bf16* __restrict__ o0, bf16* __restrict__ o1, bf16* __restrict__ o2,
    bf16* __restrict__ o3, bf16* __restrict__ o4, bf16* __restrict__ o5,
    const float* __restrict__ xin, bf16* __restrict__ lnout,
    const float* __restrict__ gp, const float* __restrict__ bp) {
  const int bi = blockIdx.x;
  const int tid = threadIdx.x;
  if (bi >= 3072) {
    // ---------------- LayerNorm (ddof=1, scalar gamma/beta) ----------
    const int row = bi - 3072;
    float v[4];
    const float* p = xin + (size_t)row * Dd + tid * 4;
#pragma unroll
    for (int i = 0; i < 4; i++) v[i] = p[i];
    float s = v[0] + v[1] + v[2] + v[3];
    float s2 = v[0] * v[0] + v[1] * v[1] + v[2] * v[2] + v[3] * v[3];
#pragma unroll
    for (int m = 1; m < 64; m <<= 1) {
      s += __shfl_xor(s, m, 64);
      s2 += __shfl_xor(s2, m, 64);
    }
    __shared__ float ls[4], ls2[4];
    if ((tid & 63) == 0) {
      ls[tid >> 6] = s;
      ls2[tid >> 6] = s2;
    }
    __syncthreads();
    s = ls[0] + ls[1] + ls[2] + ls[3];
    s2 = ls2[0] + ls2[1] + ls2[2] + ls2[3];
    float mean = s * (1.0f / Dd);
    float var = (s2 - (float)Dd * mean * mean) * (1.0f / (Dd - 1));
    var = fmaxf(var, 0.0f);
    float g = gp[0], be = bp[0];
    float rs = g / (sqrtf(var) + EPSf);
    bf16* q = lnout + (size_t)row * Dd + tid * 4;
#pragma unroll
    for (int i = 0; i < 4; i++) q[i] = (bf16)((v[i] - mean) * rs + be);
    return;
  }
  // ---------------- weight transpose ----------------
  __shared__ float t[64 * 65];
  const float* in;
  bf16* out;
  int R, C, local, sh;
  if (bi < 1024) {
    const int j = bi >> 8;
    local = bi & 255; R = 1024; C = 1024; sh = 4;
    in = (j == 0) ? i0 : (j == 1) ? i1 : (j == 2) ? i2 : i3;
    out = (j == 0) ? o0 : (j == 1) ? o1 : (j == 2) ? o2 : o3;
  } else if (bi < 2048) {
    local = bi - 1024; R = 1024; C = 4096; sh = 6; in = i4; out = o4;
  } else {
    local = bi - 2048; R = 4096; C = 1024; sh = 4; in = i5; out = o5;
  }
  const int nx = 1 << sh;
  const int bx = local & (nx - 1), by = local >> sh;
  const int tx = tid & 63, ty = tid >> 6;
  const int r0 = by * 64, c0 = bx * 64;
#pragma unroll
  for (int i = 0; i < 16; i++) {
    int r = ty + i * 4;
    t[r * 65 + tx] = in[(size_t)(r0 + r) * C + c0 + tx];
  }
  __syncthreads();
#pragma unroll
  for (int i = 0; i < 16; i++) {
    int r = ty + i * 4;
    out[(size_t)(c0 + r) * R + r0 + tx] = (bf16)t[tx * 65 + r];
  }
}

// =====================================================================
// LayerNorm reading bf16 input (x1 residual stream), bf16 out.
// =====================================================================
__global__ __launch_bounds__(256) void ln_bf16_k(
    const bf16* __restrict__ in, bf16* __restrict__ out,
    const float* __restrict__ gp, const float* __restrict__ bp) {
  const int row = blockIdx.x;
  const int tid = threadIdx.x;
  const bf16x4 vv = *(const bf16x4*)(in + (size_t)row * Dd + tid * 4);
  float v[4];
#pragma unroll
  for (int i = 0; i < 4; i++) v[i] = (float)vv[i];
  float s = v[0] + v[1] + v[2] + v[3];
  float s2 = v[0] * v[0] + v[1] * v[1] + v[2] * v[2] + v[3] * v[3];
#pragma unroll
  for (int m = 1; m < 64; m <<= 1) {
    s += __shfl_xor(s, m, 64);
    s2 += __shfl_xor(s2, m, 64);
  }
  __shared__ float ls[4], ls2[4];
  if ((tid & 63) == 0) {
    ls[tid >> 6] = s;
    ls2[tid >> 6] = s2;
  }
  __syncthreads();
  s = ls[0] + ls[1] + ls[2] + ls[3];
  s2 = ls2[0] + ls2[1] + ls2[2] + ls2[3];
  float mean = s * (1.0f / Dd);
  float var = (s2 - (float)Dd * mean * mean) * (1.0f / (Dd - 1));
  var = fmaxf(var, 0.0f);
  float g = gp[0], be = bp[0];
  float rs = g / (sqrtf(var) + EPSf);
  bf16* q = out + (size_t)row * Dd + tid * 4;
#pragma unroll
  for (int i = 0; i < 4; i++) q[i] = (bf16)((v[i] - mean) * rs + be);
}

// =====================================================================
// GEMM v2: C = A(M,K; sa) @ Bt(N,K; sb)^T + epilogue. BK=64 only.
// 128x128 tile, 4 waves, 4x4 MFMA 16x16x32, XOR swizzle, T1 remap.
// NEW: double-buffered LDS (64 KB, still 2 blocks/CU) with counted
// vmcnt(8) — next tile's 8 global_load_lds stay in flight across the
// whole compute phase (round-4-proven contract; never drains to 0 in
// the main loop). Raw s_barrier, no compiler vmcnt-0 drain.
// EPI: 1 bias+resid(f32)->f32 | 2 bias,relu->bf16 | 3 resid(f32)->f32
//      4 qkv 3-way bias; Q,K -> bf16 Cout, V -> LDS-transposed vtb
//      5 bias+resid(f32)->bf16 (WO) | 6 bias+resid(bf16 vtbr)->f32
// =====================================================================
template <int EPI, int BK>
__global__ __launch_bounds__(256) void gemm_bt(
    const bf16* __restrict__ A, const bf16* __restrict__ Bt,
    const float* __restrict__ bias, const float* __restrict__ bias2,
    const float* __restrict__ bias3, const float* __restrict__ resid,
    const bf16* __restrict__ vtbr, bf16* __restrict__ vtb,
    void* __restrict__ Cout, int M, int N, int K, int sa, int sb) {
  static_assert(BK == 64, "dbuf layout assumes BK=64");
  __shared__ __attribute__((aligned(16))) char smem[65536];  // 2 x 32 KB
  constexpr int CPR = BK / 8;       // 8-elem chunks per row
  constexpr int RPJ = 256 / CPR;    // rows staged per j-iteration
  constexpr int NJ = BK / 16;      // j-iterations per operand
  const int tid = threadIdx.x;
  const int ln = tid & 63;
  const int wv = tid >> 6;
  const int wm = wv >> 1, wn = wv & 1;
  const int quad = ln >> 4, l16 = ln & 15;
  const int l7 = l16 & 7;
  // T1 XCD-aware remap (dispatch order is x-fastest; XCD ~ d % 8)
  const int nxg = gridDim.x;
  const int d = blockIdx.y * nxg + blockIdx.x;
  const int sseq = d >> 3;
  const int bxr = sseq % nxg;
  const int byr = (d & 7) + 8 * (sseq / nxg);
  const int m0 = byr * 128, n0 = bxr * 128;

  f32x4 acc[4][4];
#pragma unroll
  for (int i = 0; i < 4; i++)
#pragma unroll
    for (int j = 0; j < 4; j++) acc[i][j] = {0.f, 0.f, 0.f, 0.f};

  const int sr = tid / CPR;                    // staging row (within j-blk)
  const int sc = (tid & (CPR - 1)) ^ (sr & 7); // swizzled source chunk
  const size_t abase = (size_t)(m0 + sr) * sa + sc * 8;
  const size_t bbase = (size_t)(n0 + sr) * sb + sc * 8;

  const int nt = K >> 6;
  int cur = 0;

  // prologue: stage tile 0 into buffer 0, full drain once
  {
#pragma unroll
    for (int j = 0; j < NJ; j++) {
      gl_lds16(A + abase + (size_t)(j * RPJ) * sa,
               (char*)smem + j * 4096 + wv * 1024);
      gl_lds16(Bt + bbase + (size_t)(j * RPJ) * sb,
               (char*)smem + 16384 + j * 4096 + wv * 1024);
    }
  }
  asm volatile("s_waitcnt vmcnt(0)" ::: "memory");
  __builtin_amdgcn_s_barrier();

  for (int t = 0; t < nt; ++t) {
    if (t + 1 < nt) {
      // issue next tile's 8 loads into the spare buffer; keep flying
      char* dl = smem + ((cur ^ 1) * 32768);
      const int koff = (t + 1) * 64;
#pragma unroll
      for (int j = 0; j < NJ; j++) {
        gl_lds16(A + abase + (size_t)(j * RPJ) * sa + koff,
                 dl + j * 4096 + wv * 1024);
        gl_lds16(Bt + bbase + (size_t)(j * RPJ) * sb + koff,
                 dl + 16384 + j * 4096 + wv * 1024);
      }
      asm volatile("s_waitcnt vmcnt(8)" ::: "memory");  // tile t landed
    } else {
      asm volatile("s_waitcnt vmcnt(0)" ::: "memory");
    }
    __builtin_amdgcn_s_barrier();

    const bf16* As = (const bf16*)(smem + cur * 32768);
    const bf16* Bs = (const bf16*)(smem + cur * 32768 + 16384);
#pragma unroll
    for (int kh = 0; kh < 2; kh++) {
      bf16x8 af[4], bfr[4];
#pragma unroll
      for (int mi = 0; mi < 4; mi++)
        af[mi] = *(const bf16x8*)&As[(wm * 64 + mi * 16 + l16) * 64 +
                                     ((kh * 4 + quad) ^ l7) * 8];
#pragma unroll
      for (int ni = 0; ni < 4; ni++)
        bfr[ni] = *(const bf16x8*)&Bs[(wn * 64 + ni * 16 + l16) * 64 +
                                      ((kh * 4 + quad) ^ l7) * 8];
#pragma unroll
      for (int mi = 0; mi < 4; mi++)
#pragma unroll
        for (int ni = 0; ni < 4; ni++)
          acc[mi][ni] = __builtin_amdgcn_mfma_f32_16x16x32_bf16(
              af[mi], bfr[ni], acc[mi][ni], 0, 0, 0);
    }
    __builtin_amdgcn_s_barrier();  // all reads of buf[cur] done
    cur ^= 1;
  }

  if constexpr (EPI == 4) {
    if (n0 < 2048) {  // Q,K -> qkv buffer (direct bf16 stores)
#pragma unroll
      for (int mi = 0; mi < 4; mi++) {
        const int m = m0 + wm * 64 + mi * 16 + quad * 4;
#pragma unroll
        for (int ni = 0; ni < 4; ni++) {
          const int n = n0 + wn * 64 + ni * 16 + l16;
          const float bvl = (n < 1024) ? bias[n] : bias2[n - 1024];
#pragma unroll
          for (int r = 0; r < 4; r++)
            ((bf16*)Cout)[(size_t)(m + r) * N + n] =
                (bf16)(acc[mi][ni][r] + bvl);
        }
      }
    } else {  // V: transpose 128x128 tile via LDS, coalesced store to vtb
      bf16* T = (bf16*)smem;  // 32 KB of the 64 KB buffer
#pragma unroll
      for (int mi = 0; mi < 4; mi++) {
        const int ml = wm * 64 + mi * 16 + quad * 4;  // local row, 4-contig
        const int c = ml >> 3, hf = (ml >> 2) & 1;
#pragma unroll
        for (int ni = 0; ni < 4; ni++) {
          const int nl = wn * 64 + ni * 16 + l16;  // local col
          const float bvl = bias3[(n0 - 2048) + nl];
          bf16x4 tv;
#pragma unroll
          for (int r = 0; r < 4; r++) tv[r] = (bf16)(acc[mi][ni][r] + bvl);
          *(bf16x4*)&T[nl * 128 + ((c ^ (nl & 15)) << 3) + (hf << 2)] = tv;
        }
      }
      __syncthreads();
      const size_t vbase =
          ((size_t)(m0 >> 10) * 1024 + (n0 - 2048)) * Ss + (m0 & 1023);
#pragma unroll
      for (int p = 0; p < 8; p++) {
        const int row = p * 16 + (tid >> 4);
        const int k = tid & 15;
        bf16x8 vv = *(const bf16x8*)&T[row * 128 + ((k ^ (row & 15)) << 3)];
        *(bf16x8*)&vtb[vbase + (size_t)row * Ss + k * 8] = vv;
      }
    }
  } else {
#pragma unroll
    for (int mi = 0; mi < 4; mi++) {
      const int m = m0 + wm * 64 + mi * 16 + quad * 4;
#pragma unroll
      for (int ni = 0; ni < 4; ni++) {
        const int n = n0 + wn * 64 + ni * 16 + l16;
        float bvl = 0.0f;
        if constexpr (EPI != 3) bvl = bias[n];
#pragma unroll
        for (int r = 0; r < 4; r++) {
          float val = acc[mi][ni][r] + bvl;
          const size_t idx = (size_t)(m + r) * N + n;
          if constexpr (EPI == 1) {
            ((float*)Cout)[idx] = val + resid[idx];
          } else if constexpr (EPI == 2) {
            ((bf16*)Cout)[idx] = (bf16)fmaxf(val, 0.0f);
          } else if constexpr (EPI == 3) {
            ((float*)Cout)[idx] = val + resid[idx];
          } else if constexpr (EPI == 5) {
            ((bf16*)Cout)[idx] = (bf16)(val + resid[idx]);
          } else {  // EPI == 6
            ((float*)Cout)[idx] = val + (float)vtbr[idx];
          }
        }
      }
    }
  }
}

// =====================================================================
// gemm256_relu v5: 4-phase, A-fragments register-resident, DEEPENED
// staging (3-3-2-0): ph0 stages B0,B1,B2; ph1 B3,A0,A2; ph2 A1,A3;
// ph3 none. Minimum load flight rises 1.5 -> 2.5 phases (~HBM lat).
// Waits (before closing barrier -> mutual):
//   end-ph0 vmcnt(3): outstanding {A1',A3',B0,B1,B2}=5 -> drains the
//     prev tile's A1,A3 before ph1 reads those chunks.
//   end-ph3 vmcnt(2): outstanding 8 -> drains B0-3,A0,A2 (next ph0's
//     reads), leaves fresh A1,A3 flying across the boundary.
// Last tile: vmcnt(0) at both points. t=0: prologue fully drained, so
// end-ph0's vmcnt(3) is a no-op on a clean pipe. Invariants traced.
// =====================================================================
__global__ __launch_bounds__(512) void gemm256_relu(
    const bf16* __restrict__ A, const bf16* __restrict__ Bt,
    const float* __restrict__ bias, bf16* __restrict__ Cout, int M, int N,
    int K, int sa, int sb) {
  __shared__ __attribute__((aligned(16))) char smem[131072];
  const int tid = threadIdx.x;
  const int ln = tid & 63;
  const int wv = tid >> 6;  // 0..7
  const int wm = wv >> 2, wn = wv & 3;
  const int quad = ln >> 4, l16 = ln & 15;
  const int l7 = l16 & 7;
  // T1 XCD-aware remap
  const int nxg = gridDim.x;
  const int d = blockIdx.y * nxg + blockIdx.x;
  const int sseq = d >> 3;
  const int bxr = sseq % nxg;
  const int byr = (d & 7) + 8 * (sseq / nxg);
  const int m0 = byr * 256, n0 = bxr * 256;

  f32x4 acc[8][4];
#pragma unroll
  for (int i = 0; i < 8; i++)
#pragma unroll
    for (int j = 0; j < 4; j++) acc[i][j] = {0.f, 0.f, 0.f, 0.f};

  const int sr = tid >> 3;              // staging row 0..63 (per chunk)
  const int sc = (tid & 7) ^ (sr & 7);  // swizzled source chunk
  const size_t abase = (size_t)(m0 + sr) * sa + sc * 8;
  const size_t bbase = (size_t)(n0 + sr) * sb + sc * 8;
  const int w8 = tid >> 6;  // wave-uniform LDS sub-base

  const int nt = K >> 6;
  int cur = 0;

  // prologue: stage tile 0 into buffer 0, full drain once
  {
#pragma unroll
    for (int j = 0; j < 4; j++) {
      gl_lds16(A + abase + (size_t)(j * 64) * sa,
               smem + j * 8192 + w8 * 1024);
      gl_lds16(Bt + bbase + (size_t)(j * 64) * sb,
               smem + 32768 + j * 8192 + w8 * 1024);
    }
  }
  asm volatile("s_waitcnt vmcnt(0)" ::: "memory");
  __builtin_amdgcn_s_barrier();

  for (int t = 0; t < nt; ++t) {
    const bf16* As = (const bf16*)(smem + cur * 65536);
    const bf16* Bs = (const bf16*)(smem + cur * 65536 + 32768);
    char* ldst = smem + (cur ^ 1) * 65536;
    const bool pf = (t + 1 < nt);
    const int koff = (t + 1) * 64;

    bf16x8 af0[4][2], af1[4][2], bfr[2][2];

    // ---- phase 0: read A(mh0)+B(nq0); stage B chunks 0,1,2 ----
#pragma unroll
    for (int mf = 0; mf < 4; mf++)
#pragma unroll
      for (int kh = 0; kh < 2; kh++)
        af0[mf][kh] = *(const bf16x8*)&As[(wm * 128 + mf * 16 + l16) * 64 +
                                          (((kh * 4 + quad) ^ l7) * 8)];
#pragma unroll
    for (int nf = 0; nf < 2; nf++)
#pragma unroll
      for (int kh = 0; kh < 2; kh++)
        bfr[nf][kh] = *(const bf16x8*)&Bs[(wn * 64 + nf * 16 + l16) * 64 +
                                          (((kh * 4 + quad) ^ l7) * 8)];
    if (pf) {
      gl_lds16(Bt + bbase + koff, ldst + 32768 + w8 * 1024);
      gl_lds16(Bt + bbase + (size_t)64 * sb + koff,
               ldst + 32768 + 8192 + w8 * 1024);
      gl_lds16(Bt + bbase + (size_t)128 * sb + koff,
               ldst + 32768 + 16384 + w8 * 1024);
    }
    __builtin_amdgcn_s_barrier();
    __builtin_amdgcn_s_setprio(1);
#pragma unroll
    for (int kh = 0; kh < 2; kh++)
#pragma unroll
      for (int mf = 0; mf < 4; mf++)
#pragma unroll
        for (int nf = 0; nf < 2; nf++)
          acc[mf][nf] = __builtin_amdgcn_mfma_f32_16x16x32_bf16(
              af0[mf][kh], bfr[nf][kh], acc[mf][nf], 0, 0, 0);
    __builtin_amdgcn_s_setprio(0);
    // prev tile's A chunks 1,3 must land before ph1 reads them
    if (pf) {
      asm volatile("s_waitcnt vmcnt(3)" ::: "memory");
    } else {
      asm volatile("s_waitcnt vmcnt(0)" ::: "memory");
    }
    __builtin_amdgcn_s_barrier();

    // ---- phase 1: read A(mh1); stage B chunk 3 + A chunks 0,2 ----
#pragma unroll
    for (int mf = 0; mf < 4; mf++)
#pragma unroll
      for (int kh = 0; kh < 2; kh++)
        af1[mf][kh] =
            *(const bf16x8*)&As[(wm * 128 + 64 + mf * 16 + l16) * 64 +
                                (((kh * 4 + quad) ^ l7) * 8)];
    if (pf) {
      gl_lds16(Bt + bbase + (size_t)192 * sb + koff,
               ldst + 32768 + 24576 + w8 * 1024);
      gl_lds16(A + abase + koff, ldst + w8 * 1024);
      gl_lds16(A + abase + (size_t)128 * sa + koff,
               ldst + 16384 + w8 * 1024);
    }
    __builtin_amdgcn_s_barrier();
    __builtin_amdgcn_s_setprio(1);
#pragma unroll
    for (int kh = 0; kh < 2; kh++)
#pragma unroll
      for (int mf = 0; mf < 4; mf++)
#pragma unroll
        for (int nf = 0; nf < 2; nf++)
          acc[4 + mf][nf] = __builtin_amdgcn_mfma_f32_16x16x32_bf16(
              af1[mf][kh], bfr[nf][kh], acc[4 + mf][nf], 0, 0, 0);
    __builtin_amdgcn_s_setprio(0);
    __builtin_amdgcn_s_barrier();

    // ---- phase 2: read B(nq1); stage A chunks 1,3 ----
#pragma unroll
    for (int nf = 0; nf < 2; nf++)
#pragma unroll
      for (int kh = 0; kh < 2; kh++)
        bfr[nf][kh] =
            *(const bf16x8*)&Bs[(wn * 64 + 32 + nf * 16 + l16) * 64 +
                                (((kh * 4 + quad) ^ l7) * 8)];
    if (pf) {
      gl_lds16(A + abase + (size_t)64 * sa + koff, ldst + 8192 + w8 * 1024);
      gl_lds16(A + abase + (size_t)192 * sa + koff,
               ldst + 24576 + w8 * 1024);
    }
    __builtin_amdgcn_s_barrier();
    __builtin_amdgcn_s_setprio(1);
#pragma unroll
    for (int kh = 0; kh < 2; kh++)
#pragma unroll
      for (int mf = 0; mf < 4; mf++)
#pragma unroll
        for (int nf = 0; nf < 2; nf++)
          acc[4 + mf][2 + nf] = __builtin_amdgcn_mfma_f32_16x16x32_bf16(
              af1[mf][kh], bfr[nf][kh], acc[4 + mf][2 + nf], 0, 0, 0);
    __builtin_amdgcn_s_setprio(0);
    __builtin_amdgcn_s_barrier();

    // ---- phase 3: NO ds_reads (af0 live); NO staging ----
    __builtin_amdgcn_s_setprio(1);
#pragma unroll
    for (int kh = 0; kh < 2; kh++)
#pragma unroll
      for (int mf = 0; mf < 4; mf++)
#pragma unroll
        for (int nf = 0; nf < 2; nf++)
          acc[mf][2 + nf] = __builtin_amdgcn_mfma_f32_16x16x32_bf16(
              af0[mf][kh], bfr[nf][kh], acc[mf][2 + nf], 0, 0, 0);
    __builtin_amdgcn_s_setprio(0);
    // boundary: everything except the fresh A1,A3 pair must be landed
    if (pf) {
      asm volatile("s_waitcnt vmcnt(2)" ::: "memory");
    } else {
      asm volatile("s_waitcnt vmcnt(0)" ::: "memory");
    }
    __builtin_amdgcn_s_barrier();
    cur ^= 1;
  }

  // epilogue: bias + relu -> bf16
#pragma unroll
  for (int mi = 0; mi < 8; mi++) {
    const int m = m0 + wm * 128 + mi * 16 + quad * 4;
#pragma unroll
    for (int ni = 0; ni < 4; ni++) {
      const int n = n0 + wn * 64 + ni * 16 + l16;
      const float bvl = bias[n];
#pragma unroll
      for (int r = 0; r < 4; r++)
        Cout[(size_t)(m + r) * N + n] =
            (bf16)fmaxf(acc[mi][ni][r] + bvl, 0.0f);
    }
  }
}

// =====================================================================
// Flash attention v3: swapped QK^T on 32x32x16 MFMA + double-buffered
// K/V staging with counted vmcnt(4) (T3/T4). 36 KB LDS, 4 blocks/CU.
// =====================================================================
__global__ __launch_bounds__(256) void attn_k(
    const bf16* __restrict__ qkv, const bf16* __restrict__ vt,
    const int* __restrict__ mask, bf16* __restrict__ ctx) {
  __shared__ __attribute__((aligned(16))) char smem[36864];
  __shared__ int Ft[16];
  bf16* Qs = (bf16*)smem;              // 16 KB (then buf1 / epi Tb)
  float* Fm = (float*)(smem + 32768);  // 4 KB
  const int tid = threadIdx.x;
  const int l = tid & 63, w = tid >> 6;
  const int lq = l & 31, lh = l >> 5;
  const int lq7 = lq & 7;
  const int bh = blockIdx.x;
  const int b = bh >> 4, h = bh & 15;
  const int q0 = blockIdx.y * 128;
  const int sr = tid >> 3;              // staging row 0..31
  const int sc = (tid & 7) ^ (sr & 7);  // swizzled source chunk

  if (tid < 16) Ft[tid] = 0;
  {  // stage Q tile (4 loads) + tile-0 K/V into buf0 (4 loads)
#pragma unroll
    for (int j = 0; j < 4; j++) {
      const size_t ga =
          (size_t)(b * Ss + q0 + j * 32 + sr) * 3072 + h * 64 + sc * 8;
      gl_lds16(qkv + ga, smem + j * 4096 + w * 1024);
    }
#pragma unroll
    for (int j = 0; j < 2; j++) {
      const size_t ga =
          (size_t)(b * Ss + j * 32 + sr) * 3072 + 1024 + h * 64 + sc * 8;
      gl_lds16(qkv + ga, smem + 16384 + j * 4096 + w * 1024);
      const size_t gv = (size_t)(bh * 64 + j * 32 + sr) * Ss + sc * 8;
      gl_lds16(vt + gv, smem + 24576 + j * 4096 + w * 1024);
    }
  }
  {  // mask -> additive log2-domain bias (0 or -inf) + per-tile flags
    const int4 mv = *(const int4*)&mask[b * Ss + tid * 4];
    const float ninf = -__builtin_inff();
    Fm[tid * 4 + 0] = mv.x ? 0.0f : ninf;
    Fm[tid * 4 + 1] = mv.y ? 0.0f : ninf;
    Fm[tid * 4 + 2] = mv.z ? 0.0f : ninf;
    Fm[tid * 4 + 3] = mv.w ? 0.0f : ninf;
    if (!(mv.x && mv.y && mv.z && mv.w)) atomicOr(&Ft[tid >> 4], 1);
  }
  __syncthreads();  // Q + tile0 K/V landed; Fm/Ft visible

  // Q B-fragments: col q = w*32+lq, k-elems d = s*16 + 8*lh + 0..7
  bf16x8 qf[4];
#pragma unroll
  for (int s = 0; s < 4; s++)
    qf[s] =
        *(const bf16x8*)&Qs[(w * 32 + lq) * 64 + (((s * 2 + lh) ^ lq7) * 8)];
  __syncthreads();  // all waves done reading Qs -> buf1 may overwrite

  f32x16 oacc[2];
#pragma unroll
  for (int d = 0; d < 2; d++)
#pragma unroll
    for (int r = 0; r < 16; r++) oacc[d][r] = 0.0f;
  float rsum = 0.0f;

  for (int t = 0; t < 16; ++t) {
    const int kk0 = t * 64;
    if (t + 1 < 16) {  // stage tile t+1 into the spare buffer
      char* dst = smem + (((t + 1) & 1) ? 0 : 16384);
      const int nk = kk0 + 64;
#pragma unroll
      for (int j = 0; j < 2; j++) {
        const size_t ga =
            (size_t)(b * Ss + nk + j * 32 + sr) * 3072 + 1024 + h * 64 +
            sc * 8;
        gl_lds16(qkv + ga, dst + j * 4096 + w * 1024);
        const size_t gv = (size_t)(bh * 64 + j * 32 + sr) * Ss + nk + sc * 8;
        gl_lds16(vt + gv, dst + 8192 + j * 4096 + w * 1024);
      }
      asm volatile("s_waitcnt vmcnt(4)" ::: "memory");  // tile t landed
    } else {
      asm volatile("s_waitcnt vmcnt(0)" ::: "memory");
    }
    __builtin_amdgcn_s_barrier();
    const bf16* Ks = (const bf16*)(smem + ((t & 1) ? 0 : 16384));
    const bf16* Vs = Ks + 4096;  // +8 KB

    // S^T[key][q]: A = K rows (keys), B = Q cols (q).
    f32x16 sacc[2];
#pragma unroll
    for (int kb = 0; kb < 2; kb++)
#pragma unroll
      for (int r = 0; r < 16; r++) sacc[kb][r] = 0.0f;

    __builtin_amdgcn_s_setprio(1);
#pragma unroll
    for (int kb = 0; kb < 2; kb++)
#pragma unroll
      for (int s = 0; s < 4; s++) {
        const bf16x8 kf = *(const bf16x8*)&Ks[(kb * 32 + lq) * 64 +
                                              (((s * 2 + lh) ^ lq7) * 8)];
        sacc[kb] = __builtin_amdgcn_mfma_f32_32x32x16_bf16(kf, qf[s],
                                                           sacc[kb], 0, 0, 0);
      }
    __builtin_amdgcn_s_setprio(0);

    if (__builtin_amdgcn_readfirstlane(Ft[t])) {
      // slow path: additive mask per key
#pragma unroll
      for (int kb = 0; kb < 2; kb++)
#pragma unroll
        for (int g = 0; g < 4; g++) {
          const f32x4 mv = *(const f32x4*)&Fm[kk0 + kb * 32 + 4 * lh + 8 * g];
#pragma unroll
          for (int j = 0; j < 4; j++)
            sacc[kb][g * 4 + j] = __builtin_amdgcn_exp2f(
                fmaf(sacc[kb][g * 4 + j], SM_SCALE, mv[j]));
        }
    } else {
#pragma unroll
      for (int kb = 0; kb < 2; kb++)
#pragma unroll
        for (int r = 0; r < 16; r++)
          sacc[kb][r] = __builtin_amdgcn_exp2f(sacc[kb][r] * SM_SCALE);
    }
    // rowsum (balanced tree; cross-half combined after the loop)
#pragma unroll
    for (int kb = 0; kb < 2; kb++) {
      const float t0 = (sacc[kb][0] + sacc[kb][1]) + (sacc[kb][2] + sacc[kb][3]);
      const float t1 = (sacc[kb][4] + sacc[kb][5]) + (sacc[kb][6] + sacc[kb][7]);
      const float t2 =
          (sacc[kb][8] + sacc[kb][9]) + (sacc[kb][10] + sacc[kb][11]);
      const float t3 =
          (sacc[kb][12] + sacc[kb][13]) + (sacc[kb][14] + sacc[kb][15]);
      rsum += ((t0 + t1) + (t2 + t3));
    }

    // pack P^T to bf16 B-frags in-register and run PV on the fly
    __builtin_amdgcn_s_setprio(1);
#pragma unroll
    for (int tt = 0; tt < 4; tt++) {
      const int kb = tt >> 1, rb = (tt & 1) * 8;
      u32 pa = cvtpk(sacc[kb][rb + 0], sacc[kb][rb + 1]);
      u32 pbv = cvtpk(sacc[kb][rb + 2], sacc[kb][rb + 3]);
      u32 pc = cvtpk(sacc[kb][rb + 4], sacc[kb][rb + 5]);
      u32 pd = cvtpk(sacc[kb][rb + 6], sacc[kb][rb + 7]);
      asm("v_permlane32_swap_b32 %0, %1" : "+v"(pa), "+v"(pc));
      asm("v_permlane32_swap_b32 %0, %1" : "+v"(pbv), "+v"(pd));
      union {
        u32 u[4];
        bf16x8 v;
      } pk;
      pk.u[0] = pa;
      pk.u[1] = pbv;
      pk.u[2] = pc;
      pk.u[3] = pd;
      const int vsw = ((tt * 2 + lh) ^ lq7) * 8;
      const bf16x8 vf0 = *(const bf16x8*)&Vs[lq * 64 + vsw];
      const bf16x8 vf1 = *(const bf16x8*)&Vs[(32 + lq) * 64 + vsw];
      oacc[0] =
          __builtin_amdgcn_mfma_f32_32x32x16_bf16(vf0, pk.v, oacc[0], 0, 0, 0);
      oacc[1] =
          __builtin_amdgcn_mfma_f32_32x32x16_bf16(vf1, pk.v, oacc[1], 0, 0, 0);
    }
    __builtin_amdgcn_s_setprio(0);
    asm volatile("s_waitcnt lgkmcnt(0)" ::: "memory");  // reads done
    __builtin_amdgcn_s_barrier();  // before buf(t&1) restaged at t+1
  }

  // combine the two lane-halves' partial rowsums (semantics-invariant)
  float xs = rsum, ys = rsum;
  asm("v_permlane32_swap_b32 %0, %1" : "+v"(xs), "+v"(ys));
  const float inv = 1.0f / (xs + ys);

  // epilogue: per-wave LDS transpose (stride 72), coalesced 16B stores.
  bf16* Tb = (bf16*)(smem + w * 4608);  // 32 rows x 72 bf16 = 4608 B
#pragma unroll
  for (int dblk = 0; dblk < 2; dblk++)
#pragma unroll
    for (int g = 0; g < 4; g++) {
      const u32 lo =
          cvtpk(oacc[dblk][g * 4 + 0] * inv, oacc[dblk][g * 4 + 1] * inv);
      const u32 hi =
          cvtpk(oacc[dblk][g * 4 + 2] * inv, oacc[dblk][g * 4 + 3] * inv);
      u32x2 pr2;
      pr2[0] = lo;
      pr2[1] = hi;
      const int dbase = dblk * 32 + 8 * g + 4 * lh;
      *(u32x2*)&Tb[lq * 72 + dbase] = pr2;
    }
  __syncthreads();
#pragma unroll
  for (int p = 0; p < 4; p++) {
    const int row = p * 8 + (l >> 3);
    const int ch = l & 7;
    const bf16x8 vv = *(const bf16x8*)&Tb[row * 72 + ch * 8];
    *(bf16x8*)&ctx[(size_t)(b * Ss + q0 + w * 32 + row) * Dd + h * 64 +
                   ch * 8] = vv;
  }
}

// =====================================================================
extern "C" void kernel_launch(void* const* d_in, const int* in_sizes, int n_in,
                              void* d_out, int out_size, void* d_ws,
                              size_t ws_size, hipStream_t stream) {
  (void)in_sizes; (void)n_in; (void)out_size;
  const float* x = (const float*)d_in[0];
  const int* mask = (const int*)d_in[1];
  const float* wq = (const float*)d_in[2];
  const float* bq = (const float*)d_in[3];
  const float* wk = (const float*)d_in[4];
  const float* bk = (const float*)d_in[5];
  const float* wvw = (const float*)d_in[6];
  const float* bv = (const float*)d_in[7];
  const float* wo = (const float*)d_in[8];
  const float* bo = (const float*)d_in[9];
  const float* w1 = (const float*)d_in[10];
  const float* b1 = (const float*)d_in[11];
  const float* w2 = (const float*)d_in[12];
  const float* b2 = (const float*)d_in[13];
  const float* g1 = (const float*)d_in[14];
  const float* be1 = (const float*)d_in[15];
  const float* g2 = (const float*)d_in[16];
  const float* be2 = (const float*)d_in[17];
  float* out = (float*)d_out;

  char* ws = (char*)d_ws;
  const size_t MB = 1024 * 1024;
  bf16* w1T = (bf16*)(ws + 0 * MB);     // 8 MB  (4096x1024)
  bf16* w2T = (bf16*)(ws + 8 * MB);     // 8 MB  (1024x4096)
  bf16* wqkvT = (bf16*)(ws + 16 * MB);  // 6 MB  (3072x1024)
  bf16* woT = (bf16*)(ws + 22 * MB);    // 2 MB
  bf16* lnb = (bf16*)(ws + 24 * MB);    // 16 MB (ln1 -> ctx -> ln2)
  bf16* qkv = (bf16*)(ws + 40 * MB);    // 48 MB (8192x3072; V slots unused)
  bf16* vtb = (bf16*)(ws + 88 * MB);    // 16 MB
  bf16* x1b = (bf16*)(ws + 40 * MB);    // 16 MB overlay (qkv dead post-WO-in)
  bf16* ctx = lnb;                      // lnb dead after QKV GEMM

  dim3 blk(256);
  // fused: weight transposes + LN1 in one dispatch
  prep_k<<<3072 + 8192, blk, 0, stream>>>(
      wq, wk, wvw, wo, w1, w2, wqkvT, wqkvT + (size_t)1024 * 1024,
      wqkvT + (size_t)2048 * 1024, woT, w1T, w2T, x, lnb, g1, be1);
  // fused QKV projection; V transposed via LDS into vtb (coalesced)
  gemm_bt<4, 64><<<dim3(24, 64), blk, 0, stream>>>(
      lnb, wqkvT, bq, bk, bv, nullptr, nullptr, vtb, qkv, 8192, 3072, 1024,
      1024, 1024);
  // attention: grid (bh, qtile) -> q-tiles of one head share an XCD L2
  attn_k<<<dim3(128, 8), blk, 0, stream>>>(qkv, vtb, mask, ctx);
  // WO + bias + residual(x fp32) -> x1 (bf16 residual stream)
  gemm_bt<5, 64><<<dim3(8, 64), blk, 0, stream>>>(
      ctx, woT, bo, nullptr, nullptr, x, nullptr, nullptr, x1b, 8192, 1024,
      1024, 1024, 1024);
  // LN2 (bf16 in)
  ln_bf16_k<<<8192, blk, 0, stream>>>(x1b, lnb, g2, be2);

  if (ws_size >= 136 * MB) {
    // single-shot FFN: mid = 8192x4096 bf16 at 72..136 MB
    bf16* mid = (bf16*)(ws + 72 * MB);
    gemm256_relu<<<dim3(16, 32), dim3(512), 0, stream>>>(
        lnb, w1T, b1, mid, 8192, 4096, 1024, 1024, 1024);
    // FFN2: bias + bf16 resid (x1b) -> f32 out
    gemm_bt<6, 64><<<dim3(8, 64), blk, 0, stream>>>(
        mid, w2T, b2, nullptr, nullptr, nullptr, x1b, nullptr, out, 8192,
        1024, 4096, 4096, 4096);
  } else {
    // chunked FFN (DFF=2048 halves), mid = 32 MB at 72..104 MB
    bf16* mid = (bf16*)(ws + 72 * MB);
    gemm256_relu<<<dim3(8, 32), dim3(512), 0, stream>>>(
        lnb, w1T, b1, mid, 8192, 2048, 1024, 1024, 1024);
    gemm_bt<6, 64><<<dim3(8, 64), blk, 0, stream>>>(
        mid, w2T, b2, nullptr, nullptr, nullptr, x1b, nullptr, out, 8192,
        1024, 2048, 2048, 4096);
    gemm256_relu<<<dim3(8, 32), dim3(512), 0, stream>>>(
        lnb, w1T + (size_t)2048 * 1024, b1 + 2048, mid, 8192, 2048, 1024,
        1024, 1024);
    gemm_bt<3, 64><<<dim3(8, 64), blk, 0, stream>>>(
        mid, w2T + 2048, nullptr, nullptr, nullptr, out, nullptr, nullptr,
        out, 8192, 1024, 2048, 2048, 4096);
  }
}